// Round 1
// baseline (3991.155 us; speedup 1.0000x reference)
//
#include <hip/hip_runtime.h>
#include <math.h>

#define NN 10000
#define NE 160000
#define NT 50000

typedef unsigned short u16;
typedef unsigned int u32;

__device__ __forceinline__ float bf2f(u16 u) { return __uint_as_float(((u32)u) << 16); }
__device__ __forceinline__ u16 f2bf(float f) {
    u32 x = __float_as_uint(f);
    return (u16)((x + 0x7fffu + ((x >> 16) & 1u)) >> 16);
}
__device__ __forceinline__ float lrelu(float x) { return x > 0.f ? x : 0.2f * x; }

// ---------------------------------------------------------------------------
// Fused point-net: h1=relu(x@W1+b1), h2=relu(h1@W2+b2), h3=relu(h2@W3+b3),
// feat = max over 128 points. bf16 LDS staging, fp32 accumulate.
// LDS: h1 (128x64 bf16, 16KB) | W2/W3blk (8192 bf16, 16KB) | h2 (128x128 bf16, 32KB)
// maxs (256 int) aliases the h1 region after layer 2.
// ---------------------------------------------------------------------------
__global__ __launch_bounds__(256) void k_pointnet(
    const float* __restrict__ x,
    const float* __restrict__ W1, const float* __restrict__ b1,
    const float* __restrict__ W2, const float* __restrict__ b2,
    const float* __restrict__ W3, const float* __restrict__ b3,
    float* __restrict__ feat)
{
    __shared__ u16 smem[32768];           // 64 KB total
    u16* h1s = smem;                      // [0, 8192)
    u16* wbs = smem + 8192;               // [8192, 16384)
    u16* h2s = smem + 16384;              // [16384, 32768)
    int* maxs = (int*)smem;               // aliases h1s after layer 2

    const int node = blockIdx.x;
    const int t = threadIdx.x;
    const float* xn = x + (size_t)node * 2048;   // 128 x 16

    // stage W2 (64x128) as bf16
    for (int i = t; i < 8192; i += 256) wbs[i] = f2bf(W2[i]);

    // layer 1 -> h1s  (outputs 128x64, dot-16, x/W1 from global via L1 broadcast)
    for (int i = t; i < 8192; i += 256) {
        int p = i >> 6, c = i & 63;
        float acc = b1[c];
        #pragma unroll
        for (int k = 0; k < 16; ++k) acc = fmaf(xn[p * 16 + k], W1[k * 64 + c], acc);
        h1s[i] = f2bf(fmaxf(acc, 0.f));
    }
    __syncthreads();

    // layer 2 -> h2s  (outputs 128x128, dot-64, 1p x 4c register tile)
    for (int it = 0; it < 16; ++it) {
        int idx = t + (it << 8);
        int p = idx >> 5;
        int c0 = (idx & 31) << 2;
        float a0 = b2[c0 + 0], a1 = b2[c0 + 1], a2 = b2[c0 + 2], a3 = b2[c0 + 3];
        const u16* hrow = h1s + p * 64;
        #pragma unroll 8
        for (int k = 0; k < 64; ++k) {
            float hv = bf2f(hrow[k]);
            uint2 wv = *(const uint2*)(wbs + k * 128 + c0);
            a0 = fmaf(hv, __uint_as_float(wv.x << 16), a0);
            a1 = fmaf(hv, __uint_as_float(wv.x & 0xffff0000u), a1);
            a2 = fmaf(hv, __uint_as_float(wv.y << 16), a2);
            a3 = fmaf(hv, __uint_as_float(wv.y & 0xffff0000u), a3);
        }
        u32 lo = (u32)f2bf(fmaxf(a0, 0.f)) | ((u32)f2bf(fmaxf(a1, 0.f)) << 16);
        u32 hi = (u32)f2bf(fmaxf(a2, 0.f)) | ((u32)f2bf(fmaxf(a3, 0.f)) << 16);
        *(uint2*)(h2s + p * 128 + c0) = make_uint2(lo, hi);
    }
    __syncthreads();
    maxs[t] = 0;   // h1 region is dead now; init running max (post-relu values >= 0)

    // layer 3 in 4 column blocks of 64 channels (W3 block staged in LDS)
    for (int cb = 0; cb < 4; ++cb) {
        for (int i = t; i < 8192; i += 256) {
            int k = i >> 6, cl = i & 63;
            wbs[i] = f2bf(W3[k * 256 + (cb << 6) + cl]);
        }
        __syncthreads();   // also makes maxs init visible before first atomic
        for (int it = 0; it < 8; ++it) {
            int idx = t + (it << 8);
            int p = idx >> 4;
            int c0 = (idx & 15) << 2;
            int cg = (cb << 6) + c0;
            float a0 = b3[cg + 0], a1 = b3[cg + 1], a2 = b3[cg + 2], a3 = b3[cg + 3];
            const u16* hrow = h2s + p * 128;
            #pragma unroll 8
            for (int k = 0; k < 128; ++k) {
                float hv = bf2f(hrow[k]);
                uint2 wv = *(const uint2*)(wbs + k * 64 + c0);
                a0 = fmaf(hv, __uint_as_float(wv.x << 16), a0);
                a1 = fmaf(hv, __uint_as_float(wv.x & 0xffff0000u), a1);
                a2 = fmaf(hv, __uint_as_float(wv.y << 16), a2);
                a3 = fmaf(hv, __uint_as_float(wv.y & 0xffff0000u), a3);
            }
            atomicMax(maxs + cg + 0, __float_as_int(fmaxf(a0, 0.f)));
            atomicMax(maxs + cg + 1, __float_as_int(fmaxf(a1, 0.f)));
            atomicMax(maxs + cg + 2, __float_as_int(fmaxf(a2, 0.f)));
            atomicMax(maxs + cg + 3, __float_as_int(fmaxf(a3, 0.f)));
        }
        __syncthreads();
    }
    feat[(size_t)node * 256 + t] = __int_as_float(maxs[t]);
}

// ---------------------------------------------------------------------------
// CSR build
// ---------------------------------------------------------------------------
__global__ void k_init(int* counts, float* s1, float* s2) {
    int i = blockIdx.x * 256 + threadIdx.x;
    if (i < NN) counts[i] = 0;
    if (i < 512) { s1[i] = 0.f; s2[i] = 0.f; }
}

__global__ void k_csr_count(const int* __restrict__ EI, int* counts) {
    int e = blockIdx.x * 256 + threadIdx.x;
    if (e < NE) atomicAdd(&counts[EI[NE + e]], 1);
}

__global__ __launch_bounds__(1024) void k_scan(const int* __restrict__ counts,
                                               int* offs, int* cursor) {
    __shared__ int buf[1024];
    int t = threadIdx.x;
    int carry = 0;
    for (int chunk = 0; chunk < (NN + 1023) / 1024; ++chunk) {
        int i = chunk * 1024 + t;
        int v = (i < NN) ? counts[i] : 0;
        buf[t] = v;
        __syncthreads();
        for (int o = 1; o < 1024; o <<= 1) {
            int xv = (t >= o) ? buf[t - o] : 0;
            __syncthreads();
            buf[t] += xv;
            __syncthreads();
        }
        int excl = buf[t] - v;
        if (i < NN) { offs[i] = carry + excl; cursor[i] = carry + excl; }
        carry += buf[1023];
        __syncthreads();
    }
    if (t == 0) offs[NN] = carry;
}

__global__ void k_csr_scatter(const int* __restrict__ EI, int* cursor, int* csrc) {
    int e = blockIdx.x * 256 + threadIdx.x;
    if (e < NE) {
        int d = EI[NE + e];
        int pos = atomicAdd(&cursor[d], 1);
        csrc[pos] = EI[e];  // src node
    }
}

// ---------------------------------------------------------------------------
// Neighbor aggregation (gather over CSR). MODE 0: mean. MODE 1: self + sum (GIN).
// blockDim == W
// ---------------------------------------------------------------------------
template<int W, int MODE>
__global__ void k_agg(const float* __restrict__ in, float* __restrict__ out,
                      const int* __restrict__ offs, const int* __restrict__ srcs)
{
    int node = blockIdx.x;
    int c = threadIdx.x;
    int o0 = offs[node], o1 = offs[node + 1];
    float s = 0.f;
    for (int j = o0; j < o1; ++j) {
        int sc = srcs[j];
        s += in[(size_t)sc * W + c];
    }
    if (MODE == 0) {
        int d = o1 - o0;
        out[(size_t)node * W + c] = s / (float)(d > 0 ? d : 1);
    } else {
        out[(size_t)node * W + c] = s + in[(size_t)node * W + c];
    }
}

// ---------------------------------------------------------------------------
// Generic fp32 tiled GEMM: C[N,M] = act( A@W (+ A2@W2) + bias ), with modes.
// OUTM: 0 -> C = v ; 1 -> C = scale*v ; 2 -> C += scale*v (scale = scale_ptr[idx])
// NORM: A loaded as (A - mu[k]) * inv[k]
// 64x64 tile, BK=16, 256 threads, 4x4 per thread.
// ---------------------------------------------------------------------------
template<int RELU, int DUAL, int OUTM, int NORM>
__global__ __launch_bounds__(256) void k_gemm(
    const float* __restrict__ A, const float* __restrict__ W,
    const float* __restrict__ A2, const float* __restrict__ W2,
    const float* __restrict__ bias, float* __restrict__ C,
    int N, int K, int M,
    const float* __restrict__ scale_ptr, int scale_idx,
    const float* __restrict__ mu, const float* __restrict__ inv)
{
    __shared__ float As[16][65];
    __shared__ float Bs[16][64];
    __shared__ float As2[DUAL ? 16 : 1][65];
    __shared__ float Bs2[DUAL ? 16 : 1][64];

    const int t = threadIdx.x;
    const int col0 = blockIdx.x << 6;
    const int row0 = blockIdx.y << 6;
    const int tx = t & 15, ty = t >> 4;
    float acc[4][4] = {};

    for (int k0 = 0; k0 < K; k0 += 16) {
        #pragma unroll
        for (int j = 0; j < 4; ++j) {
            int i = t + (j << 8);
            int k = i & 15, n = i >> 4;
            int r = row0 + n;
            float v = 0.f, v2 = 0.f;
            if (r < N) {
                v = A[(size_t)r * K + k0 + k];
                if (NORM) v = (v - mu[k0 + k]) * inv[k0 + k];
                if (DUAL) v2 = A2[(size_t)r * K + k0 + k];
            }
            As[k][n] = v;
            if (DUAL) As2[k][n] = v2;
        }
        #pragma unroll
        for (int j = 0; j < 4; ++j) {
            int i = t + (j << 8);
            int cc = i & 63, k = i >> 6;
            int cg = col0 + cc;
            float v = 0.f, v2 = 0.f;
            if (cg < M) {
                v = W[(size_t)(k0 + k) * M + cg];
                if (DUAL) v2 = W2[(size_t)(k0 + k) * M + cg];
            }
            Bs[k][cc] = v;
            if (DUAL) Bs2[k][cc] = v2;
        }
        __syncthreads();
        #pragma unroll
        for (int kk = 0; kk < 16; ++kk) {
            float av[4], bv[4];
            #pragma unroll
            for (int i2 = 0; i2 < 4; ++i2) av[i2] = As[kk][(ty << 2) + i2];
            #pragma unroll
            for (int j2 = 0; j2 < 4; ++j2) bv[j2] = Bs[kk][(tx << 2) + j2];
            #pragma unroll
            for (int i2 = 0; i2 < 4; ++i2)
                #pragma unroll
                for (int j2 = 0; j2 < 4; ++j2)
                    acc[i2][j2] = fmaf(av[i2], bv[j2], acc[i2][j2]);
            if (DUAL) {
                float av2[4], bv2[4];
                #pragma unroll
                for (int i2 = 0; i2 < 4; ++i2) av2[i2] = As2[kk][(ty << 2) + i2];
                #pragma unroll
                for (int j2 = 0; j2 < 4; ++j2) bv2[j2] = Bs2[kk][(tx << 2) + j2];
                #pragma unroll
                for (int i2 = 0; i2 < 4; ++i2)
                    #pragma unroll
                    for (int j2 = 0; j2 < 4; ++j2)
                        acc[i2][j2] = fmaf(av2[i2], bv2[j2], acc[i2][j2]);
            }
        }
        __syncthreads();
    }

    float scale = 1.f;
    if (OUTM >= 1) scale = scale_ptr[scale_idx];
    #pragma unroll
    for (int i2 = 0; i2 < 4; ++i2) {
        int r = row0 + (ty << 2) + i2;
        if (r >= N) continue;
        #pragma unroll
        for (int j2 = 0; j2 < 4; ++j2) {
            int cg = col0 + (tx << 2) + j2;
            if (cg >= M) continue;
            float v = acc[i2][j2];
            if (bias) v += bias[cg];
            if (RELU) v = fmaxf(v, 0.f);
            size_t o = (size_t)r * M + cg;
            if (OUTM == 0) C[o] = v;
            else if (OUTM == 1) C[o] = scale * v;
            else C[o] += scale * v;
        }
    }
}

// ---------------------------------------------------------------------------
// GAT
// ---------------------------------------------------------------------------
__global__ void k_gat1_al(const float* __restrict__ h, const float* __restrict__ a_s,
                          const float* __restrict__ a_d, float* als, float* ald) {
    int idx = blockIdx.x * 64 + threadIdx.x;   // node*8 + head
    if (idx >= NN * 8) return;
    int node = idx >> 3, hh = idx & 7;
    float s = 0.f, d = 0.f;
    #pragma unroll
    for (int c = 0; c < 10; ++c) {
        float hv = h[node * 80 + hh * 10 + c];
        s = fmaf(hv, a_s[hh * 10 + c], s);
        d = fmaf(hv, a_d[hh * 10 + c], d);
    }
    als[idx] = s; ald[idx] = d;
}

__global__ __launch_bounds__(128) void k_gat1_attn(
    const float* __restrict__ h, const float* __restrict__ als,
    const float* __restrict__ ald, const float* __restrict__ bias,
    const int* __restrict__ offs, const int* __restrict__ srcs,
    float* __restrict__ ha)
{
    int node = blockIdx.x;
    int t = threadIdx.x;
    if (t >= 80) return;
    int hh = t / 10;
    int o0 = offs[node], o1 = offs[node + 1];
    float ad = ald[node * 8 + hh];
    float eself = lrelu(als[node * 8 + hh] + ad);
    float m = eself;
    for (int j = o0; j < o1; ++j) {
        int sc = srcs[j];
        m = fmaxf(m, lrelu(als[sc * 8 + hh] + ad));
    }
    float den = 0.f, num = 0.f;
    {
        float w = __expf(eself - m);
        den += w; num += w * h[(size_t)node * 80 + t];
    }
    for (int j = o0; j < o1; ++j) {
        int sc = srcs[j];
        float w = __expf(lrelu(als[sc * 8 + hh] + ad) - m);
        den += w; num += w * h[(size_t)sc * 80 + t];
    }
    ha[(size_t)node * 80 + t] = fmaxf(num / den + bias[t], 0.f);
}

__global__ __launch_bounds__(256) void k_gat2_al(
    const float* __restrict__ h, const float* __restrict__ a_s,
    const float* __restrict__ a_d, float* als, float* ald)
{
    __shared__ float rs[256], rd[256];
    int node = blockIdx.x, t = threadIdx.x;
    float h0 = h[(size_t)node * 512 + t], h1 = h[(size_t)node * 512 + 256 + t];
    rs[t] = h0 * a_s[t] + h1 * a_s[256 + t];
    rd[t] = h0 * a_d[t] + h1 * a_d[256 + t];
    __syncthreads();
    for (int o = 128; o > 0; o >>= 1) {
        if (t < o) { rs[t] += rs[t + o]; rd[t] += rd[t + o]; }
        __syncthreads();
    }
    if (t == 0) { als[node] = rs[0]; ald[node] = rd[0]; }
}

__global__ __launch_bounds__(256) void k_gat2_attn(
    const float* __restrict__ h, const float* __restrict__ als,
    const float* __restrict__ ald, const float* __restrict__ bias,
    const int* __restrict__ offs, const int* __restrict__ srcs,
    const float* __restrict__ fusion_w, float* __restrict__ Y)
{
    int node = blockIdx.x;
    int t = threadIdx.x;
    float w2 = fusion_w[2];
    int o0 = offs[node], o1 = offs[node + 1];
    float ad = ald[node];
    float eself = lrelu(als[node] + ad);
    float m = eself;
    for (int j = o0; j < o1; ++j) m = fmaxf(m, lrelu(als[srcs[j]] + ad));
    float den = 0.f, n0 = 0.f, n1 = 0.f;
    {
        float w = __expf(eself - m);
        den += w;
        n0 += w * h[(size_t)node * 512 + t];
        n1 += w * h[(size_t)node * 512 + 256 + t];
    }
    for (int j = o0; j < o1; ++j) {
        int sc = srcs[j];
        float w = __expf(lrelu(als[sc] + ad) - m);
        den += w;
        n0 += w * h[(size_t)sc * 512 + t];
        n1 += w * h[(size_t)sc * 512 + 256 + t];
    }
    Y[(size_t)node * 512 + t]       += w2 * (n0 / den + bias[t]);
    Y[(size_t)node * 512 + 256 + t] += w2 * (n1 / den + bias[256 + t]);
}

// ---------------------------------------------------------------------------
// BatchNorm stats + final pair scoring
// ---------------------------------------------------------------------------
__global__ __launch_bounds__(256) void k_bn_stats(const float* __restrict__ Y,
                                                  float* ssum, float* ssq) {
    int t = threadIdx.x;
    int b = blockIdx.x;   // 250 blocks x 40 rows
    int r0 = b * 40, r1 = r0 + 40;
    if (r1 > NN) r1 = NN;
    float s0 = 0, s1 = 0, q0 = 0, q1 = 0;
    for (int r = r0; r < r1; ++r) {
        float v0 = Y[(size_t)r * 512 + t];
        float v1 = Y[(size_t)r * 512 + 256 + t];
        s0 += v0; q0 += v0 * v0; s1 += v1; q1 += v1 * v1;
    }
    atomicAdd(&ssum[t], s0); atomicAdd(&ssum[256 + t], s1);
    atomicAdd(&ssq[t], q0);  atomicAdd(&ssq[256 + t], q1);
}

__global__ void k_bn_final(const float* ssum, const float* ssq, float* mu, float* inv) {
    int c = blockIdx.x * 256 + threadIdx.x;
    if (c < 512) {
        float m = ssum[c] / (float)NN;
        float v = ssq[c] / (float)NN - m * m;
        mu[c] = m;
        inv[c] = rsqrtf(v + 1e-5f);
    }
}

__global__ __launch_bounds__(256) void k_final(
    const float* __restrict__ y2, const int* __restrict__ EI,
    const int* __restrict__ tid, const float* __restrict__ fcW,
    const float* __restrict__ fcb, float* __restrict__ out)
{
    int pair = blockIdx.x * 4 + (threadIdx.x >> 6);
    int lane = threadIdx.x & 63;
    if (pair >= NT) return;
    int eid = tid[pair];
    int a = EI[eid], b = EI[NE + eid];
    float acc[7] = {};
    for (int c = lane; c < 512; c += 64) {
        float v = y2[(size_t)a * 512 + c] * y2[(size_t)b * 512 + c];
        #pragma unroll
        for (int j = 0; j < 7; ++j) acc[j] = fmaf(v, fcW[c * 7 + j], acc[j]);
    }
    for (int o = 32; o > 0; o >>= 1) {
        #pragma unroll
        for (int j = 0; j < 7; ++j) acc[j] += __shfl_down(acc[j], o);
    }
    if (lane == 0) {
        #pragma unroll
        for (int j = 0; j < 7; ++j) out[(size_t)pair * 7 + j] = acc[j] + fcb[j];
    }
}

// ---------------------------------------------------------------------------
extern "C" void kernel_launch(void* const* d_in, const int* in_sizes, int n_in,
                              void* d_out, int out_size, void* d_ws, size_t ws_size,
                              hipStream_t stream)
{
    (void)in_sizes; (void)n_in; (void)out_size; (void)ws_size;
    const float* x        = (const float*)d_in[0];
    const int*   EI       = (const int*)d_in[1];
    const int*   tid      = (const int*)d_in[2];
    const float* Wp1      = (const float*)d_in[3];
    const float* bp1      = (const float*)d_in[4];
    const float* Wp2      = (const float*)d_in[5];
    const float* bp2      = (const float*)d_in[6];
    const float* Wp3      = (const float*)d_in[7];
    const float* bp3      = (const float*)d_in[8];
    const float* sage1_Wl = (const float*)d_in[9];
    const float* sage1_bl = (const float*)d_in[10];
    const float* sage1_Wr = (const float*)d_in[11];
    const float* sage2_Wl = (const float*)d_in[12];
    const float* sage2_bl = (const float*)d_in[13];
    const float* sage2_Wr = (const float*)d_in[14];
    const float* gin1_W1  = (const float*)d_in[15];
    const float* gin1_b1  = (const float*)d_in[16];
    const float* gin1_W2  = (const float*)d_in[17];
    const float* gin1_b2  = (const float*)d_in[18];
    const float* gin2_W1  = (const float*)d_in[19];
    const float* gin2_b1  = (const float*)d_in[20];
    const float* gin2_W2  = (const float*)d_in[21];
    const float* gin2_b2  = (const float*)d_in[22];
    const float* gin_lin_W= (const float*)d_in[23];
    const float* gin_lin_b= (const float*)d_in[24];
    const float* gat1_W   = (const float*)d_in[25];
    const float* gat1_as  = (const float*)d_in[26];
    const float* gat1_ad  = (const float*)d_in[27];
    const float* gat1_b   = (const float*)d_in[28];
    const float* gat2_W   = (const float*)d_in[29];
    const float* gat2_as  = (const float*)d_in[30];
    const float* gat2_ad  = (const float*)d_in[31];
    const float* gat2_b   = (const float*)d_in[32];
    const float* fusion_w = (const float*)d_in[33];
    const float* lin1_W   = (const float*)d_in[34];
    const float* lin1_b   = (const float*)d_in[35];
    const float* lin2_W   = (const float*)d_in[36];
    const float* lin2_b   = (const float*)d_in[37];
    const float* fc2_W    = (const float*)d_in[38];
    const float* fc2_b    = (const float*)d_in[39];

    float* ws   = (float*)d_ws;
    float* feat = ws;                    // 10000 x 256
    float* B1   = feat + 2560000;        // 10000 x 512
    float* B2   = B1 + 5120000;          // 10000 x 512
    float* B3   = B2 + 5120000;          // 10000 x 128
    float* B4   = B3 + 1280000;          // 10000 x 128
    float* Y    = B4 + 1280000;          // 10000 x 512
    float* als1 = Y + 5120000;           // 10000 x 8
    float* ald1 = als1 + 80000;
    float* als2 = ald1 + 80000;          // 10000
    float* ald2 = als2 + 10000;
    float* ssum = ald2 + 10000;          // 512
    float* ssq  = ssum + 512;
    float* mu   = ssq + 512;
    float* inv  = mu + 512;
    int* counts = (int*)(inv + 512);     // 10000
    int* offs   = counts + 10000;        // 10001
    int* cursor = offs + 10001;          // 10000
    int* csrc   = cursor + 10000;        // 160000

    dim3 g128(2, 157), g512(8, 157), g80(2, 157);

    k_init<<<40, 256, 0, stream>>>(counts, ssum, ssq);
    k_pointnet<<<NN, 256, 0, stream>>>(x, Wp1, bp1, Wp2, bp2, Wp3, bp3, feat);
    k_csr_count<<<(NE + 255) / 256, 256, 0, stream>>>(EI, counts);
    k_scan<<<1, 1024, 0, stream>>>(counts, offs, cursor);
    k_csr_scatter<<<(NE + 255) / 256, 256, 0, stream>>>(EI, cursor, csrc);

    // SAGE1 / GIN1 aggregations on feat
    k_agg<256, 0><<<NN, 256, 0, stream>>>(feat, B1, offs, csrc);   // mean1
    k_agg<256, 1><<<NN, 256, 0, stream>>>(feat, B2, offs, csrc);   // gin agg1

    // hs = relu(mean1@Wl + bl + feat@Wr)
    k_gemm<1,1,0,0><<<g128, 256, 0, stream>>>(B1, sage1_Wl, feat, sage1_Wr, sage1_bl,
                                              B3, NN, 256, 128, nullptr, 0, nullptr, nullptr);
    // GIN layer1: h = relu(agg1@W1+b1); hg1 = relu(h@W2+b2)
    k_gemm<1,0,0,0><<<g128, 256, 0, stream>>>(B2, gin1_W1, nullptr, nullptr, gin1_b1,
                                              B4, NN, 256, 128, nullptr, 0, nullptr, nullptr);
    k_gemm<1,0,0,0><<<g128, 256, 0, stream>>>(B4, gin1_W2, nullptr, nullptr, gin1_b2,
                                              B2, NN, 128, 128, nullptr, 0, nullptr, nullptr);
    // GAT1: h = feat @ gat1_W (no bias)
    k_gemm<0,0,0,0><<<g80, 256, 0, stream>>>(feat, gat1_W, nullptr, nullptr, nullptr,
                                             B4, NN, 256, 80, nullptr, 0, nullptr, nullptr);
    k_gat1_al<<<1250, 64, 0, stream>>>(B4, gat1_as, gat1_ad, als1, ald1);
    k_gat1_attn<<<NN, 128, 0, stream>>>(B4, als1, ald1, gat1_b, offs, csrc, B1); // ha -> B1

    // SAGE2: mean2 = mean(hs); Y = w0*(mean2@Wl + bl + hs@Wr)
    k_agg<128, 0><<<NN, 128, 0, stream>>>(B3, B4, offs, csrc);     // mean2 -> B4
    k_gemm<0,1,1,0><<<g512, 256, 0, stream>>>(B4, sage2_Wl, B3, sage2_Wr, sage2_bl,
                                              Y, NN, 128, 512, fusion_w, 0, nullptr, nullptr);
    // GIN2: agg2 = hg1 + sum(hg1); h = relu(agg2@W1+b1); hg2 = relu(h@W2+b2); Y += w1*(hg2@lin+b)
    k_agg<128, 1><<<NN, 128, 0, stream>>>(B2, B3, offs, csrc);     // agg2 -> B3
    k_gemm<1,0,0,0><<<g128, 256, 0, stream>>>(B3, gin2_W1, nullptr, nullptr, gin2_b1,
                                              B4, NN, 128, 128, nullptr, 0, nullptr, nullptr);
    k_gemm<1,0,0,0><<<g128, 256, 0, stream>>>(B4, gin2_W2, nullptr, nullptr, gin2_b2,
                                              B3, NN, 128, 128, nullptr, 0, nullptr, nullptr);
    k_gemm<0,0,2,0><<<g512, 256, 0, stream>>>(B3, gin_lin_W, nullptr, nullptr, gin_lin_b,
                                              Y, NN, 128, 512, fusion_w, 1, nullptr, nullptr);
    // GAT2: h2 = ha @ gat2_W; attention; Y += w2*(out + b)
    k_gemm<0,0,0,0><<<g512, 256, 0, stream>>>(B1, gat2_W, nullptr, nullptr, nullptr,
                                              B2, NN, 80, 512, nullptr, 0, nullptr, nullptr);
    k_gat2_al<<<NN, 256, 0, stream>>>(B2, gat2_as, gat2_ad, als2, ald2);
    k_gat2_attn<<<NN, 256, 0, stream>>>(B2, als2, ald2, gat2_b, offs, csrc, fusion_w, Y);

    // BN + MLP head
    k_bn_stats<<<250, 256, 0, stream>>>(Y, ssum, ssq);
    k_bn_final<<<2, 256, 0, stream>>>(ssum, ssq, mu, inv);
    k_gemm<1,0,0,1><<<g512, 256, 0, stream>>>(Y, lin1_W, nullptr, nullptr, lin1_b,
                                              B1, NN, 512, 512, nullptr, 0, mu, inv);
    k_gemm<0,0,0,0><<<g512, 256, 0, stream>>>(B1, lin2_W, nullptr, nullptr, lin2_b,
                                              B2, NN, 512, 512, nullptr, 0, nullptr, nullptr);

    // final pair scoring
    k_final<<<(NT + 3) / 4, 256, 0, stream>>>(B2, EI, tid, fc2_W, fc2_b, (float*)d_out);
}

// Round 2
// 1017.618 us; speedup vs baseline: 3.9221x; 3.9221x over previous
//
#include <hip/hip_runtime.h>
#include <math.h>

#define NN 10000
#define NE 160000
#define NT 50000

typedef unsigned short u16;
typedef unsigned int u32;
typedef __attribute__((ext_vector_type(8))) short bf16x8;
typedef __attribute__((ext_vector_type(4))) float f32x4;

__device__ __forceinline__ float bf2f(u16 u) { return __uint_as_float(((u32)u) << 16); }
__device__ __forceinline__ u16 f2bf(float f) {
    u32 x = __float_as_uint(f);
    return (u16)((x + 0x7fffu + ((x >> 16) & 1u)) >> 16);
}
__device__ __forceinline__ float lrelu(float x) { return x > 0.f ? x : 0.2f * x; }

#define MFMA16(a, b, c) __builtin_amdgcn_mfma_f32_16x16x32_bf16((a), (b), (c), 0, 0, 0)

// ---------------------------------------------------------------------------
// Prep: convert x to bf16 (pairs packed in u32)
// ---------------------------------------------------------------------------
__global__ void k_cvt_x(const float* __restrict__ x, u32* __restrict__ xb) {
    const int total = NN * 128 * 8;   // u32 count
    for (int i = blockIdx.x * 256 + threadIdx.x; i < total; i += gridDim.x * 256) {
        float2 v = ((const float2*)x)[i];
        xb[i] = (u32)f2bf(v.x) | ((u32)f2bf(v.y) << 16);
    }
}

// ---------------------------------------------------------------------------
// Prep: pack W1/W2/W3 into MFMA B-fragment order, bf16.
// B-frag layout (16x16x32): lane l holds B[k = ks*32 + (l>>4)*8 + e][n = nt*16 + (l&15)]
// W1f: [nt=4][64][8] (K=16 zero-padded to 32)   W2f: [ks=2][nt=8][64][8]
// W3f: [ks=4][nt=16][64][8]
// ---------------------------------------------------------------------------
__global__ void k_wfrag(const float* __restrict__ W1, const float* __restrict__ W2,
                        const float* __restrict__ W3,
                        u16* __restrict__ W1f, u16* __restrict__ W2f, u16* __restrict__ W3f) {
    int i = blockIdx.x * 256 + threadIdx.x;
    if (i < 2048) {
        int e = i & 7, l = (i >> 3) & 63, nt = i >> 9;
        int k = (l >> 4) * 8 + e, c = nt * 16 + (l & 15);
        W1f[i] = (k < 16) ? f2bf(W1[k * 64 + c]) : (u16)0;
    }
    if (i < 8192) {
        int e = i & 7, l = (i >> 3) & 63, nt = (i >> 9) & 7, ks = i >> 12;
        int k = ks * 32 + (l >> 4) * 8 + e, c = nt * 16 + (l & 15);
        W2f[i] = f2bf(W2[k * 128 + c]);
    }
    if (i < 32768) {
        int e = i & 7, l = (i >> 3) & 63, nt = (i >> 9) & 15, ks = i >> 13;
        int k = ks * 32 + (l >> 4) * 8 + e, c = nt * 16 + (l & 15);
        W3f[i] = f2bf(W3[k * 256 + c]);
    }
}

// ---------------------------------------------------------------------------
// MFMA point-net. Per block = 1 node, 4 waves.
// L1: waves split M (32 rows each), out h1[128][64] LDS (swizzled bf16)
// L2: waves split M, out h2[128][128] LDS (swizzled bf16)
// L3: waves split N (64 cols each), in-register max-pool over 128 rows
// A-frag (16x16x32): lane l holds A[m = mt*16 + (l&15)][k = ks*32 + (l>>4)*8 + e]
// D-frag: lane l, reg r -> D[row = (l>>4)*4 + r][col = l&15]
// LDS swizzle: elem_idx ^= (row & 7) << 3   (byte ^= (row&7)<<4)
// ---------------------------------------------------------------------------
__global__ __launch_bounds__(256) void k_pointnet_mfma(
    const u16* __restrict__ xb,
    const u16* __restrict__ W1f, const float* __restrict__ b1,
    const u16* __restrict__ W2f, const float* __restrict__ b2,
    const u16* __restrict__ W3f, const float* __restrict__ b3,
    float* __restrict__ feat)
{
    __shared__ u16 h1s[8192];    // 128 x 64
    __shared__ u16 h2s[16384];   // 128 x 128

    const int node = blockIdx.x;
    const int t = threadIdx.x;
    const int w = t >> 6;        // wave 0..3
    const int l = t & 63;
    const int lr = l & 15;
    const int lg = l >> 4;

    const f32x4 zf = {0.f, 0.f, 0.f, 0.f};

    // ---------------- layer 1: rows w*32..w*32+31 ----------------
    {
        bf16x8 a0 = {0,0,0,0,0,0,0,0}, a1 = a0;
        if (lg < 2) {
            const u16* px = xb + ((size_t)node * 128 + w * 32 + lr) * 16 + lg * 8;
            a0 = *(const bf16x8*)px;
            a1 = *(const bf16x8*)(px + 256);   // +16 rows * 16 cols
        }
        f32x4 acc[2][4];
        #pragma unroll
        for (int nt = 0; nt < 4; ++nt) {
            bf16x8 bf_ = *(const bf16x8*)(W1f + (nt * 64 + l) * 8);
            acc[0][nt] = MFMA16(a0, bf_, zf);
            acc[1][nt] = MFMA16(a1, bf_, zf);
        }
        #pragma unroll
        for (int mt = 0; mt < 2; ++mt) {
            #pragma unroll
            for (int nt = 0; nt < 4; ++nt) {
                float bias = b1[nt * 16 + lr];
                #pragma unroll
                for (int r = 0; r < 4; ++r) {
                    int row = w * 32 + mt * 16 + lg * 4 + r;
                    int col = nt * 16 + lr;
                    float v = fmaxf(acc[mt][nt][r] + bias, 0.f);
                    h1s[(row * 64 + col) ^ ((row & 7) << 3)] = f2bf(v);
                }
            }
        }
    }
    __syncthreads();

    // ---------------- layer 2: rows w*32..+31, all 128 cols ----------------
    #pragma unroll
    for (int mt = 0; mt < 2; ++mt) {
        const int m0 = w * 32 + mt * 16;
        f32x4 acc2[8];
        #pragma unroll
        for (int nt = 0; nt < 8; ++nt) acc2[nt] = zf;
        #pragma unroll
        for (int ks = 0; ks < 2; ++ks) {
            int row = m0 + lr;
            int elem = row * 64 + ks * 32 + lg * 8;
            bf16x8 af = *(const bf16x8*)&h1s[elem ^ ((row & 7) << 3)];
            #pragma unroll
            for (int nt = 0; nt < 8; ++nt) {
                bf16x8 bf_ = *(const bf16x8*)(W2f + ((ks * 8 + nt) * 64 + l) * 8);
                acc2[nt] = MFMA16(af, bf_, acc2[nt]);
            }
        }
        #pragma unroll
        for (int nt = 0; nt < 8; ++nt) {
            float bias = b2[nt * 16 + lr];
            #pragma unroll
            for (int r = 0; r < 4; ++r) {
                int row = m0 + lg * 4 + r;
                int col = nt * 16 + lr;
                float v = fmaxf(acc2[nt][r] + bias, 0.f);
                h2s[(row * 128 + col) ^ ((row & 7) << 3)] = f2bf(v);
            }
        }
    }
    __syncthreads();

    // ---------------- layer 3: cols w*64..+63, all 128 rows, max-pool ------
    {
        float pmax[4] = {0.f, 0.f, 0.f, 0.f};
        #pragma unroll
        for (int half = 0; half < 2; ++half) {
            f32x4 acc3[4][4];
            #pragma unroll
            for (int mt = 0; mt < 4; ++mt)
                #pragma unroll
                for (int nt = 0; nt < 4; ++nt) acc3[mt][nt] = zf;
            #pragma unroll
            for (int ks = 0; ks < 4; ++ks) {
                bf16x8 bf_[4];
                #pragma unroll
                for (int nt = 0; nt < 4; ++nt)
                    bf_[nt] = *(const bf16x8*)(W3f + ((ks * 16 + w * 4 + nt) * 64 + l) * 8);
                #pragma unroll
                for (int mt = 0; mt < 4; ++mt) {
                    int row = half * 64 + mt * 16 + lr;
                    int elem = row * 128 + ks * 32 + lg * 8;
                    bf16x8 af = *(const bf16x8*)&h2s[elem ^ ((row & 7) << 3)];
                    #pragma unroll
                    for (int nt = 0; nt < 4; ++nt)
                        acc3[mt][nt] = MFMA16(af, bf_[nt], acc3[mt][nt]);
                }
            }
            #pragma unroll
            for (int nt = 0; nt < 4; ++nt) {
                float bias = b3[w * 64 + nt * 16 + lr];
                #pragma unroll
                for (int mt = 0; mt < 4; ++mt)
                    #pragma unroll
                    for (int r = 0; r < 4; ++r)
                        pmax[nt] = fmaxf(pmax[nt], fmaxf(acc3[mt][nt][r] + bias, 0.f));
            }
        }
        #pragma unroll
        for (int nt = 0; nt < 4; ++nt) {
            pmax[nt] = fmaxf(pmax[nt], __shfl_xor(pmax[nt], 16));
            pmax[nt] = fmaxf(pmax[nt], __shfl_xor(pmax[nt], 32));
        }
        if (l < 16) {
            #pragma unroll
            for (int nt = 0; nt < 4; ++nt)
                feat[(size_t)node * 256 + w * 64 + nt * 16 + l] = pmax[nt];
        }
    }
}

// ---------------------------------------------------------------------------
// CSR build
// ---------------------------------------------------------------------------
__global__ void k_init(int* counts, float* s1, float* s2) {
    int i = blockIdx.x * 256 + threadIdx.x;
    if (i < NN) counts[i] = 0;
    if (i < 512) { s1[i] = 0.f; s2[i] = 0.f; }
}

__global__ void k_csr_count(const int* __restrict__ EI, int* counts) {
    int e = blockIdx.x * 256 + threadIdx.x;
    if (e < NE) atomicAdd(&counts[EI[NE + e]], 1);
}

__global__ __launch_bounds__(1024) void k_scan(const int* __restrict__ counts,
                                               int* offs, int* cursor) {
    __shared__ int buf[1024];
    int t = threadIdx.x;
    int carry = 0;
    for (int chunk = 0; chunk < (NN + 1023) / 1024; ++chunk) {
        int i = chunk * 1024 + t;
        int v = (i < NN) ? counts[i] : 0;
        buf[t] = v;
        __syncthreads();
        for (int o = 1; o < 1024; o <<= 1) {
            int xv = (t >= o) ? buf[t - o] : 0;
            __syncthreads();
            buf[t] += xv;
            __syncthreads();
        }
        int excl = buf[t] - v;
        if (i < NN) { offs[i] = carry + excl; cursor[i] = carry + excl; }
        carry += buf[1023];
        __syncthreads();
    }
    if (t == 0) offs[NN] = carry;
}

__global__ void k_csr_scatter(const int* __restrict__ EI, int* cursor, int* csrc) {
    int e = blockIdx.x * 256 + threadIdx.x;
    if (e < NE) {
        int d = EI[NE + e];
        int pos = atomicAdd(&cursor[d], 1);
        csrc[pos] = EI[e];
    }
}

// ---------------------------------------------------------------------------
// Neighbor aggregation. MODE 0: mean. MODE 1: self + sum (GIN).
// ---------------------------------------------------------------------------
template<int W, int MODE>
__global__ void k_agg(const float* __restrict__ in, float* __restrict__ out,
                      const int* __restrict__ offs, const int* __restrict__ srcs)
{
    int node = blockIdx.x;
    int c = threadIdx.x;
    int o0 = offs[node], o1 = offs[node + 1];
    float s = 0.f;
    for (int j = o0; j < o1; ++j) {
        int sc = srcs[j];
        s += in[(size_t)sc * W + c];
    }
    if (MODE == 0) {
        int d = o1 - o0;
        out[(size_t)node * W + c] = s / (float)(d > 0 ? d : 1);
    } else {
        out[(size_t)node * W + c] = s + in[(size_t)node * W + c];
    }
}

// ---------------------------------------------------------------------------
// Generic fp32 tiled GEMM (as round 1)
// ---------------------------------------------------------------------------
template<int RELU, int DUAL, int OUTM, int NORM>
__global__ __launch_bounds__(256) void k_gemm(
    const float* __restrict__ A, const float* __restrict__ W,
    const float* __restrict__ A2, const float* __restrict__ W2,
    const float* __restrict__ bias, float* __restrict__ C,
    int N, int K, int M,
    const float* __restrict__ scale_ptr, int scale_idx,
    const float* __restrict__ mu, const float* __restrict__ inv)
{
    __shared__ float As[16][65];
    __shared__ float Bs[16][64];
    __shared__ float As2[DUAL ? 16 : 1][65];
    __shared__ float Bs2[DUAL ? 16 : 1][64];

    const int t = threadIdx.x;
    const int col0 = blockIdx.x << 6;
    const int row0 = blockIdx.y << 6;
    const int tx = t & 15, ty = t >> 4;
    float acc[4][4] = {};

    for (int k0 = 0; k0 < K; k0 += 16) {
        #pragma unroll
        for (int j = 0; j < 4; ++j) {
            int i = t + (j << 8);
            int k = i & 15, n = i >> 4;
            int r = row0 + n;
            float v = 0.f, v2 = 0.f;
            if (r < N) {
                v = A[(size_t)r * K + k0 + k];
                if (NORM) v = (v - mu[k0 + k]) * inv[k0 + k];
                if (DUAL) v2 = A2[(size_t)r * K + k0 + k];
            }
            As[k][n] = v;
            if (DUAL) As2[k][n] = v2;
        }
        #pragma unroll
        for (int j = 0; j < 4; ++j) {
            int i = t + (j << 8);
            int cc = i & 63, k = i >> 6;
            int cg = col0 + cc;
            float v = 0.f, v2 = 0.f;
            if (cg < M) {
                v = W[(size_t)(k0 + k) * M + cg];
                if (DUAL) v2 = W2[(size_t)(k0 + k) * M + cg];
            }
            Bs[k][cc] = v;
            if (DUAL) Bs2[k][cc] = v2;
        }
        __syncthreads();
        #pragma unroll
        for (int kk = 0; kk < 16; ++kk) {
            float av[4], bv[4];
            #pragma unroll
            for (int i2 = 0; i2 < 4; ++i2) av[i2] = As[kk][(ty << 2) + i2];
            #pragma unroll
            for (int j2 = 0; j2 < 4; ++j2) bv[j2] = Bs[kk][(tx << 2) + j2];
            #pragma unroll
            for (int i2 = 0; i2 < 4; ++i2)
                #pragma unroll
                for (int j2 = 0; j2 < 4; ++j2)
                    acc[i2][j2] = fmaf(av[i2], bv[j2], acc[i2][j2]);
            if (DUAL) {
                float av2[4], bv2[4];
                #pragma unroll
                for (int i2 = 0; i2 < 4; ++i2) av2[i2] = As2[kk][(ty << 2) + i2];
                #pragma unroll
                for (int j2 = 0; j2 < 4; ++j2) bv2[j2] = Bs2[kk][(tx << 2) + j2];
                #pragma unroll
                for (int i2 = 0; i2 < 4; ++i2)
                    #pragma unroll
                    for (int j2 = 0; j2 < 4; ++j2)
                        acc[i2][j2] = fmaf(av2[i2], bv2[j2], acc[i2][j2]);
            }
        }
        __syncthreads();
    }

    float scale = 1.f;
    if (OUTM >= 1) scale = scale_ptr[scale_idx];
    #pragma unroll
    for (int i2 = 0; i2 < 4; ++i2) {
        int r = row0 + (ty << 2) + i2;
        if (r >= N) continue;
        #pragma unroll
        for (int j2 = 0; j2 < 4; ++j2) {
            int cg = col0 + (tx << 2) + j2;
            if (cg >= M) continue;
            float v = acc[i2][j2];
            if (bias) v += bias[cg];
            if (RELU) v = fmaxf(v, 0.f);
            size_t o = (size_t)r * M + cg;
            if (OUTM == 0) C[o] = v;
            else if (OUTM == 1) C[o] = scale * v;
            else C[o] += scale * v;
        }
    }
}

// ---------------------------------------------------------------------------
// GAT
// ---------------------------------------------------------------------------
__global__ void k_gat1_al(const float* __restrict__ h, const float* __restrict__ a_s,
                          const float* __restrict__ a_d, float* als, float* ald) {
    int idx = blockIdx.x * 64 + threadIdx.x;
    if (idx >= NN * 8) return;
    int node = idx >> 3, hh = idx & 7;
    float s = 0.f, d = 0.f;
    #pragma unroll
    for (int c = 0; c < 10; ++c) {
        float hv = h[node * 80 + hh * 10 + c];
        s = fmaf(hv, a_s[hh * 10 + c], s);
        d = fmaf(hv, a_d[hh * 10 + c], d);
    }
    als[idx] = s; ald[idx] = d;
}

__global__ __launch_bounds__(128) void k_gat1_attn(
    const float* __restrict__ h, const float* __restrict__ als,
    const float* __restrict__ ald, const float* __restrict__ bias,
    const int* __restrict__ offs, const int* __restrict__ srcs,
    float* __restrict__ ha)
{
    int node = blockIdx.x;
    int t = threadIdx.x;
    if (t >= 80) return;
    int hh = t / 10;
    int o0 = offs[node], o1 = offs[node + 1];
    float ad = ald[node * 8 + hh];
    float eself = lrelu(als[node * 8 + hh] + ad);
    float m = eself;
    for (int j = o0; j < o1; ++j) {
        int sc = srcs[j];
        m = fmaxf(m, lrelu(als[sc * 8 + hh] + ad));
    }
    float den = 0.f, num = 0.f;
    {
        float wgt = __expf(eself - m);
        den += wgt; num += wgt * h[(size_t)node * 80 + t];
    }
    for (int j = o0; j < o1; ++j) {
        int sc = srcs[j];
        float wgt = __expf(lrelu(als[sc * 8 + hh] + ad) - m);
        den += wgt; num += wgt * h[(size_t)sc * 80 + t];
    }
    ha[(size_t)node * 80 + t] = fmaxf(num / den + bias[t], 0.f);
}

__global__ __launch_bounds__(256) void k_gat2_al(
    const float* __restrict__ h, const float* __restrict__ a_s,
    const float* __restrict__ a_d, float* als, float* ald)
{
    __shared__ float rs[256], rd[256];
    int node = blockIdx.x, t = threadIdx.x;
    float h0 = h[(size_t)node * 512 + t], h1 = h[(size_t)node * 512 + 256 + t];
    rs[t] = h0 * a_s[t] + h1 * a_s[256 + t];
    rd[t] = h0 * a_d[t] + h1 * a_d[256 + t];
    __syncthreads();
    for (int o = 128; o > 0; o >>= 1) {
        if (t < o) { rs[t] += rs[t + o]; rd[t] += rd[t + o]; }
        __syncthreads();
    }
    if (t == 0) { als[node] = rs[0]; ald[node] = rd[0]; }
}

__global__ __launch_bounds__(256) void k_gat2_attn(
    const float* __restrict__ h, const float* __restrict__ als,
    const float* __restrict__ ald, const float* __restrict__ bias,
    const int* __restrict__ offs, const int* __restrict__ srcs,
    const float* __restrict__ fusion_w, float* __restrict__ Y)
{
    int node = blockIdx.x;
    int t = threadIdx.x;
    float w2 = fusion_w[2];
    int o0 = offs[node], o1 = offs[node + 1];
    float ad = ald[node];
    float eself = lrelu(als[node] + ad);
    float m = eself;
    for (int j = o0; j < o1; ++j) m = fmaxf(m, lrelu(als[srcs[j]] + ad));
    float den = 0.f, n0 = 0.f, n1 = 0.f;
    {
        float wgt = __expf(eself - m);
        den += wgt;
        n0 += wgt * h[(size_t)node * 512 + t];
        n1 += wgt * h[(size_t)node * 512 + 256 + t];
    }
    for (int j = o0; j < o1; ++j) {
        int sc = srcs[j];
        float wgt = __expf(lrelu(als[sc] + ad) - m);
        den += wgt;
        n0 += wgt * h[(size_t)sc * 512 + t];
        n1 += wgt * h[(size_t)sc * 512 + 256 + t];
    }
    Y[(size_t)node * 512 + t]       += w2 * (n0 / den + bias[t]);
    Y[(size_t)node * 512 + 256 + t] += w2 * (n1 / den + bias[256 + t]);
}

// ---------------------------------------------------------------------------
// BatchNorm stats + final pair scoring
// ---------------------------------------------------------------------------
__global__ __launch_bounds__(256) void k_bn_stats(const float* __restrict__ Y,
                                                  float* ssum, float* ssq) {
    int t = threadIdx.x;
    int b = blockIdx.x;
    int r0 = b * 40, r1 = r0 + 40;
    if (r1 > NN) r1 = NN;
    float s0 = 0, s1 = 0, q0 = 0, q1 = 0;
    for (int r = r0; r < r1; ++r) {
        float v0 = Y[(size_t)r * 512 + t];
        float v1 = Y[(size_t)r * 512 + 256 + t];
        s0 += v0; q0 += v0 * v0; s1 += v1; q1 += v1 * v1;
    }
    atomicAdd(&ssum[t], s0); atomicAdd(&ssum[256 + t], s1);
    atomicAdd(&ssq[t], q0);  atomicAdd(&ssq[256 + t], q1);
}

__global__ void k_bn_final(const float* ssum, const float* ssq, float* mu, float* inv) {
    int c = blockIdx.x * 256 + threadIdx.x;
    if (c < 512) {
        float m = ssum[c] / (float)NN;
        float v = ssq[c] / (float)NN - m * m;
        mu[c] = m;
        inv[c] = rsqrtf(v + 1e-5f);
    }
}

__global__ __launch_bounds__(256) void k_final(
    const float* __restrict__ y2, const int* __restrict__ EI,
    const int* __restrict__ tid, const float* __restrict__ fcW,
    const float* __restrict__ fcb, float* __restrict__ out)
{
    int pair = blockIdx.x * 4 + (threadIdx.x >> 6);
    int lane = threadIdx.x & 63;
    if (pair >= NT) return;
    int eid = tid[pair];
    int a = EI[eid], b = EI[NE + eid];
    float acc[7] = {};
    for (int c = lane; c < 512; c += 64) {
        float v = y2[(size_t)a * 512 + c] * y2[(size_t)b * 512 + c];
        #pragma unroll
        for (int j = 0; j < 7; ++j) acc[j] = fmaf(v, fcW[c * 7 + j], acc[j]);
    }
    for (int o = 32; o > 0; o >>= 1) {
        #pragma unroll
        for (int j = 0; j < 7; ++j) acc[j] += __shfl_down(acc[j], o);
    }
    if (lane == 0) {
        #pragma unroll
        for (int j = 0; j < 7; ++j) out[(size_t)pair * 7 + j] = acc[j] + fcb[j];
    }
}

// ---------------------------------------------------------------------------
extern "C" void kernel_launch(void* const* d_in, const int* in_sizes, int n_in,
                              void* d_out, int out_size, void* d_ws, size_t ws_size,
                              hipStream_t stream)
{
    (void)in_sizes; (void)n_in; (void)out_size; (void)ws_size;
    const float* x        = (const float*)d_in[0];
    const int*   EI       = (const int*)d_in[1];
    const int*   tid      = (const int*)d_in[2];
    const float* Wp1      = (const float*)d_in[3];
    const float* bp1      = (const float*)d_in[4];
    const float* Wp2      = (const float*)d_in[5];
    const float* bp2      = (const float*)d_in[6];
    const float* Wp3      = (const float*)d_in[7];
    const float* bp3      = (const float*)d_in[8];
    const float* sage1_Wl = (const float*)d_in[9];
    const float* sage1_bl = (const float*)d_in[10];
    const float* sage1_Wr = (const float*)d_in[11];
    const float* sage2_Wl = (const float*)d_in[12];
    const float* sage2_bl = (const float*)d_in[13];
    const float* sage2_Wr = (const float*)d_in[14];
    const float* gin1_W1  = (const float*)d_in[15];
    const float* gin1_b1  = (const float*)d_in[16];
    const float* gin1_W2  = (const float*)d_in[17];
    const float* gin1_b2  = (const float*)d_in[18];
    const float* gin2_W1  = (const float*)d_in[19];
    const float* gin2_b1  = (const float*)d_in[20];
    const float* gin2_W2  = (const float*)d_in[21];
    const float* gin2_b2  = (const float*)d_in[22];
    const float* gin_lin_W= (const float*)d_in[23];
    const float* gin_lin_b= (const float*)d_in[24];
    const float* gat1_W   = (const float*)d_in[25];
    const float* gat1_as  = (const float*)d_in[26];
    const float* gat1_ad  = (const float*)d_in[27];
    const float* gat1_b   = (const float*)d_in[28];
    const float* gat2_W   = (const float*)d_in[29];
    const float* gat2_as  = (const float*)d_in[30];
    const float* gat2_ad  = (const float*)d_in[31];
    const float* gat2_b   = (const float*)d_in[32];
    const float* fusion_w = (const float*)d_in[33];
    const float* lin1_W   = (const float*)d_in[34];
    const float* lin1_b   = (const float*)d_in[35];
    const float* lin2_W   = (const float*)d_in[36];
    const float* lin2_b   = (const float*)d_in[37];
    const float* fc2_W    = (const float*)d_in[38];
    const float* fc2_b    = (const float*)d_in[39];

    float* ws   = (float*)d_ws;
    float* feat = ws;                    // 10000 x 256
    float* B1   = feat + 2560000;        // 10000 x 512
    float* B2   = B1 + 5120000;          // 10000 x 512
    float* B3   = B2 + 5120000;          // 10000 x 128
    float* B4   = B3 + 1280000;          // 10000 x 128
    float* Y    = B4 + 1280000;          // 10000 x 512
    float* als1 = Y + 5120000;           // 10000 x 8
    float* ald1 = als1 + 80000;
    float* als2 = ald1 + 80000;
    float* ald2 = als2 + 10000;
    float* ssum = ald2 + 10000;
    float* ssq  = ssum + 512;
    float* mu   = ssq + 512;
    float* inv  = mu + 512;
    int* counts = (int*)(inv + 512);     // 10000
    int* offs   = counts + 10000;        // 10001
    int* cursor = offs + 10001;          // 10000
    int* csrc   = cursor + 10000;        // 160000
    u16* W1f    = (u16*)(csrc + 160000); // 2048
    u16* W2f    = W1f + 2048;            // 8192
    u16* W3f    = W2f + 8192;            // 32768

    // x as bf16: alias the B2..Y region (dead until after pointnet)
    u16* xb = (u16*)B2;                  // 10000*128*16 u16 = 40.96 MB

    dim3 g128(2, 157), g512(8, 157), g80(2, 157);

    k_init<<<40, 256, 0, stream>>>(counts, ssum, ssq);
    k_cvt_x<<<2048, 256, 0, stream>>>(x, (u32*)xb);
    k_wfrag<<<128, 256, 0, stream>>>(Wp1, Wp2, Wp3, W1f, W2f, W3f);
    k_pointnet_mfma<<<NN, 256, 0, stream>>>(xb, W1f, bp1, W2f, bp2, W3f, bp3, feat);
    k_csr_count<<<(NE + 255) / 256, 256, 0, stream>>>(EI, counts);
    k_scan<<<1, 1024, 0, stream>>>(counts, offs, cursor);
    k_csr_scatter<<<(NE + 255) / 256, 256, 0, stream>>>(EI, cursor, csrc);

    // SAGE1 / GIN1 aggregations on feat
    k_agg<256, 0><<<NN, 256, 0, stream>>>(feat, B1, offs, csrc);
    k_agg<256, 1><<<NN, 256, 0, stream>>>(feat, B2, offs, csrc);

    k_gemm<1,1,0,0><<<g128, 256, 0, stream>>>(B1, sage1_Wl, feat, sage1_Wr, sage1_bl,
                                              B3, NN, 256, 128, nullptr, 0, nullptr, nullptr);
    k_gemm<1,0,0,0><<<g128, 256, 0, stream>>>(B2, gin1_W1, nullptr, nullptr, gin1_b1,
                                              B4, NN, 256, 128, nullptr, 0, nullptr, nullptr);
    k_gemm<1,0,0,0><<<g128, 256, 0, stream>>>(B4, gin1_W2, nullptr, nullptr, gin1_b2,
                                              B2, NN, 128, 128, nullptr, 0, nullptr, nullptr);
    k_gemm<0,0,0,0><<<g80, 256, 0, stream>>>(feat, gat1_W, nullptr, nullptr, nullptr,
                                             B4, NN, 256, 80, nullptr, 0, nullptr, nullptr);
    k_gat1_al<<<1250, 64, 0, stream>>>(B4, gat1_as, gat1_ad, als1, ald1);
    k_gat1_attn<<<NN, 128, 0, stream>>>(B4, als1, ald1, gat1_b, offs, csrc, B1);

    k_agg<128, 0><<<NN, 128, 0, stream>>>(B3, B4, offs, csrc);
    k_gemm<0,1,1,0><<<g512, 256, 0, stream>>>(B4, sage2_Wl, B3, sage2_Wr, sage2_bl,
                                              Y, NN, 128, 512, fusion_w, 0, nullptr, nullptr);
    k_agg<128, 1><<<NN, 128, 0, stream>>>(B2, B3, offs, csrc);
    k_gemm<1,0,0,0><<<g128, 256, 0, stream>>>(B3, gin2_W1, nullptr, nullptr, gin2_b1,
                                              B4, NN, 128, 128, nullptr, 0, nullptr, nullptr);
    k_gemm<1,0,0,0><<<g128, 256, 0, stream>>>(B4, gin2_W2, nullptr, nullptr, gin2_b2,
                                              B3, NN, 128, 128, nullptr, 0, nullptr, nullptr);
    k_gemm<0,0,2,0><<<g512, 256, 0, stream>>>(B3, gin_lin_W, nullptr, nullptr, gin_lin_b,
                                              Y, NN, 128, 512, fusion_w, 1, nullptr, nullptr);
    k_gemm<0,0,0,0><<<g512, 256, 0, stream>>>(B1, gat2_W, nullptr, nullptr, nullptr,
                                              B2, NN, 80, 512, nullptr, 0, nullptr, nullptr);
    k_gat2_al<<<NN, 256, 0, stream>>>(B2, gat2_as, gat2_ad, als2, ald2);
    k_gat2_attn<<<NN, 256, 0, stream>>>(B2, als2, ald2, gat2_b, offs, csrc, fusion_w, Y);

    k_bn_stats<<<250, 256, 0, stream>>>(Y, ssum, ssq);
    k_bn_final<<<2, 256, 0, stream>>>(ssum, ssq, mu, inv);
    k_gemm<1,0,0,1><<<g512, 256, 0, stream>>>(Y, lin1_W, nullptr, nullptr, lin1_b,
                                              B1, NN, 512, 512, nullptr, 0, mu, inv);
    k_gemm<0,0,0,0><<<g512, 256, 0, stream>>>(B1, lin2_W, nullptr, nullptr, lin2_b,
                                              B2, NN, 512, 512, nullptr, 0, nullptr, nullptr);

    k_final<<<(NT + 3) / 4, 256, 0, stream>>>(B2, EI, tid, fc2_W, fc2_b, (float*)d_out);
}

// Round 5
// 733.310 us; speedup vs baseline: 5.4427x; 1.3877x over previous
//
#include <hip/hip_runtime.h>
#include <math.h>

#define NN 10000
#define NE 160000
#define NT 50000

typedef unsigned short u16;
typedef unsigned int u32;
typedef __attribute__((ext_vector_type(8))) short bf16x8;
typedef __attribute__((ext_vector_type(4))) float f32x4;

__device__ __forceinline__ float bf2f(u16 u) { return __uint_as_float(((u32)u) << 16); }
__device__ __forceinline__ u16 f2bf(float f) {
    u32 x = __float_as_uint(f);
    return (u16)((x + 0x7fffu + ((x >> 16) & 1u)) >> 16);
}
__device__ __forceinline__ float lrelu(float x) { return x > 0.f ? x : 0.2f * x; }

#define MFMA16(a, b, c) __builtin_amdgcn_mfma_f32_16x16x32_bf16((a), (b), (c), 0, 0, 0)

// ---------------------------------------------------------------------------
// Prep: convert x to bf16
// ---------------------------------------------------------------------------
__global__ void k_cvt_x(const float* __restrict__ x, u32* __restrict__ xb) {
    const int total = NN * 128 * 8;
    for (int i = blockIdx.x * 256 + threadIdx.x; i < total; i += gridDim.x * 256) {
        float2 v = ((const float2*)x)[i];
        xb[i] = (u32)f2bf(v.x) | ((u32)f2bf(v.y) << 16);
    }
}

// ---------------------------------------------------------------------------
// Prep: pack pointnet W1/W2/W3 into MFMA B-fragment order
// ---------------------------------------------------------------------------
__global__ void k_wfrag(const float* __restrict__ W1, const float* __restrict__ W2,
                        const float* __restrict__ W3,
                        u16* __restrict__ W1f, u16* __restrict__ W2f, u16* __restrict__ W3f) {
    int i = blockIdx.x * 256 + threadIdx.x;
    if (i < 2048) {
        int e = i & 7, l = (i >> 3) & 63, nt = i >> 9;
        int k = (l >> 4) * 8 + e, c = nt * 16 + (l & 15);
        W1f[i] = (k < 16) ? f2bf(W1[k * 64 + c]) : (u16)0;
    }
    if (i < 8192) {
        int e = i & 7, l = (i >> 3) & 63, nt = (i >> 9) & 7, ks = i >> 12;
        int k = ks * 32 + (l >> 4) * 8 + e, c = nt * 16 + (l & 15);
        W2f[i] = f2bf(W2[k * 128 + c]);
    }
    if (i < 32768) {
        int e = i & 7, l = (i >> 3) & 63, nt = (i >> 9) & 15, ks = i >> 13;
        int k = ks * 32 + (l >> 4) * 8 + e, c = nt * 16 + (l & 15);
        W3f[i] = f2bf(W3[k * 256 + c]);
    }
}

// ---------------------------------------------------------------------------
// Generic weight pack: fp32 [K x M] -> bf16 frag order [ceil64(K)/32][M/16][64][8]
// ---------------------------------------------------------------------------
__global__ void k_pack(const float* __restrict__ W, u16* __restrict__ Wf, int K, int Mt) {
    int total = (((K + 63) & ~63) >> 5) * Mt * 512;
    for (int i = blockIdx.x * 256 + threadIdx.x; i < total; i += gridDim.x * 256) {
        int e = i & 7, l = (i >> 3) & 63, mt = (i >> 9) % Mt, kk = i / (Mt << 9);
        int k = (kk << 5) + ((l >> 4) << 3) + e;
        int c = (mt << 4) + (l & 15);
        Wf[i] = (k < K) ? f2bf(W[(size_t)k * (Mt << 4) + c]) : (u16)0;
    }
}

// ---------------------------------------------------------------------------
// MFMA point-net (bf16 feat out)
// ---------------------------------------------------------------------------
__global__ __launch_bounds__(256) void k_pointnet_mfma(
    const u16* __restrict__ xb,
    const u16* __restrict__ W1f, const float* __restrict__ b1,
    const u16* __restrict__ W2f, const float* __restrict__ b2,
    const u16* __restrict__ W3f, const float* __restrict__ b3,
    u16* __restrict__ featb)
{
    __shared__ u16 h1s[8192];
    __shared__ u16 h2s[16384];

    const int node = blockIdx.x;
    const int t = threadIdx.x;
    const int w = t >> 6;
    const int l = t & 63;
    const int lr = l & 15;
    const int lg = l >> 4;

    const f32x4 zf = {0.f, 0.f, 0.f, 0.f};

    // layer 1
    {
        bf16x8 a0 = {0,0,0,0,0,0,0,0}, a1 = a0;
        if (lg < 2) {
            const u16* px = xb + ((size_t)node * 128 + w * 32 + lr) * 16 + lg * 8;
            a0 = *(const bf16x8*)px;
            a1 = *(const bf16x8*)(px + 256);
        }
        f32x4 acc[2][4];
        #pragma unroll
        for (int nt = 0; nt < 4; ++nt) {
            bf16x8 bf_ = *(const bf16x8*)(W1f + (nt * 64 + l) * 8);
            acc[0][nt] = MFMA16(a0, bf_, zf);
            acc[1][nt] = MFMA16(a1, bf_, zf);
        }
        #pragma unroll
        for (int mt = 0; mt < 2; ++mt) {
            #pragma unroll
            for (int nt = 0; nt < 4; ++nt) {
                float bias = b1[nt * 16 + lr];
                #pragma unroll
                for (int r = 0; r < 4; ++r) {
                    int row = w * 32 + mt * 16 + lg * 4 + r;
                    int col = nt * 16 + lr;
                    float v = fmaxf(acc[mt][nt][r] + bias, 0.f);
                    h1s[(row * 64 + col) ^ ((row & 7) << 3)] = f2bf(v);
                }
            }
        }
    }
    __syncthreads();

    // layer 2
    #pragma unroll
    for (int mt = 0; mt < 2; ++mt) {
        const int m0 = w * 32 + mt * 16;
        f32x4 acc2[8];
        #pragma unroll
        for (int nt = 0; nt < 8; ++nt) acc2[nt] = zf;
        #pragma unroll
        for (int ks = 0; ks < 2; ++ks) {
            int row = m0 + lr;
            int elem = row * 64 + ks * 32 + lg * 8;
            bf16x8 af = *(const bf16x8*)&h1s[elem ^ ((row & 7) << 3)];
            #pragma unroll
            for (int nt = 0; nt < 8; ++nt) {
                bf16x8 bf_ = *(const bf16x8*)(W2f + ((ks * 8 + nt) * 64 + l) * 8);
                acc2[nt] = MFMA16(af, bf_, acc2[nt]);
            }
        }
        #pragma unroll
        for (int nt = 0; nt < 8; ++nt) {
            float bias = b2[nt * 16 + lr];
            #pragma unroll
            for (int r = 0; r < 4; ++r) {
                int row = m0 + lg * 4 + r;
                int col = nt * 16 + lr;
                float v = fmaxf(acc2[nt][r] + bias, 0.f);
                h2s[(row * 128 + col) ^ ((row & 7) << 3)] = f2bf(v);
            }
        }
    }
    __syncthreads();

    // layer 3 + max-pool
    {
        float pmax[4] = {0.f, 0.f, 0.f, 0.f};
        #pragma unroll
        for (int half = 0; half < 2; ++half) {
            f32x4 acc3[4][4];
            #pragma unroll
            for (int mt = 0; mt < 4; ++mt)
                #pragma unroll
                for (int nt = 0; nt < 4; ++nt) acc3[mt][nt] = zf;
            #pragma unroll
            for (int ks = 0; ks < 4; ++ks) {
                bf16x8 bf_[4];
                #pragma unroll
                for (int nt = 0; nt < 4; ++nt)
                    bf_[nt] = *(const bf16x8*)(W3f + ((ks * 16 + w * 4 + nt) * 64 + l) * 8);
                #pragma unroll
                for (int mt = 0; mt < 4; ++mt) {
                    int row = half * 64 + mt * 16 + lr;
                    int elem = row * 128 + ks * 32 + lg * 8;
                    bf16x8 af = *(const bf16x8*)&h2s[elem ^ ((row & 7) << 3)];
                    #pragma unroll
                    for (int nt = 0; nt < 4; ++nt)
                        acc3[mt][nt] = MFMA16(af, bf_[nt], acc3[mt][nt]);
                }
            }
            #pragma unroll
            for (int nt = 0; nt < 4; ++nt) {
                float bias = b3[w * 64 + nt * 16 + lr];
                #pragma unroll
                for (int mt = 0; mt < 4; ++mt)
                    #pragma unroll
                    for (int r = 0; r < 4; ++r)
                        pmax[nt] = fmaxf(pmax[nt], fmaxf(acc3[mt][nt][r] + bias, 0.f));
            }
        }
        #pragma unroll
        for (int nt = 0; nt < 4; ++nt) {
            pmax[nt] = fmaxf(pmax[nt], __shfl_xor(pmax[nt], 16));
            pmax[nt] = fmaxf(pmax[nt], __shfl_xor(pmax[nt], 32));
        }
        if (l < 16) {
            #pragma unroll
            for (int nt = 0; nt < 4; ++nt)
                featb[(size_t)node * 256 + w * 64 + nt * 16 + l] = f2bf(pmax[nt]);
        }
    }
}

// ---------------------------------------------------------------------------
// Generic bf16 MFMA GEMM. A: [N x K] bf16 row-major; Bf packed frag order.
// 128-row block, BK=64, 4 waves split M (32 rows each), CT col-tiles of 16.
// OUTM: 0 bf16 out; 1 fp32 out = scale*v; 2 fp32 out += scale*v; 3 fp32 out.
// NOTE: template param must NOT be named NT (macro collision with #define NT).
// ---------------------------------------------------------------------------
template<int CT, int DUAL, int RELU, int OUTM>
__global__ __launch_bounds__(256) void k_mm(
    const u16* __restrict__ A, const u16* __restrict__ A2,
    const u16* __restrict__ Bf, const u16* __restrict__ B2f,
    const float* __restrict__ bias, int K, int Mt,
    void* __restrict__ outp,
    const float* __restrict__ scale_ptr, int scale_idx)
{
    __shared__ u16 As[8192];
    __shared__ u16 As2[DUAL ? 8192 : 8];

    const int t = threadIdx.x;
    const int l = t & 63, lr = l & 15, lg = l >> 4;
    const int row0 = blockIdx.y << 7;
    const int ct0 = blockIdx.x * CT;
    const int m0 = (t >> 6) << 5;

    const f32x4 zf = {0.f, 0.f, 0.f, 0.f};
    f32x4 acc[2][CT];
    #pragma unroll
    for (int mt = 0; mt < 2; ++mt)
        #pragma unroll
        for (int nt = 0; nt < CT; ++nt) acc[mt][nt] = zf;

    const int KS = (K + 63) >> 6;
    for (int kblk = 0; kblk < KS; ++kblk) {
        const int k0 = kblk << 6;
        #pragma unroll
        for (int j = 0; j < 4; ++j) {
            int si = t + (j << 8);
            int row = si >> 3, seg = si & 7;
            int gr = row0 + row;
            int kb = k0 + (seg << 3);
            bf16x8 v = {0,0,0,0,0,0,0,0};
            bf16x8 v2 = {0,0,0,0,0,0,0,0};
            if (gr < NN) {
                if (kb + 8 <= K) {
                    v = *(const bf16x8*)(A + (size_t)gr * K + kb);
                    if (DUAL) v2 = *(const bf16x8*)(A2 + (size_t)gr * K + kb);
                } else {
                    #pragma unroll
                    for (int e = 0; e < 8; ++e) if (kb + e < K) {
                        v[e] = (short)A[(size_t)gr * K + kb + e];
                        if (DUAL) v2[e] = (short)A2[(size_t)gr * K + kb + e];
                    }
                }
            }
            int soff = ((row << 6) + (seg << 3)) ^ ((row & 7) << 3);
            *(bf16x8*)&As[soff] = v;
            if (DUAL) *(bf16x8*)&As2[soff] = v2;
        }
        __syncthreads();
        #pragma unroll
        for (int ks = 0; ks < 2; ++ks) {
            const int kk = (k0 >> 5) + ks;
            bf16x8 bfr[CT];
            #pragma unroll
            for (int nt = 0; nt < CT; ++nt)
                bfr[nt] = *(const bf16x8*)(Bf + (((size_t)kk * Mt + ct0 + nt) << 9) + (l << 3));
            #pragma unroll
            for (int mt = 0; mt < 2; ++mt) {
                int row = m0 + (mt << 4) + lr;
                int soff = ((row << 6) + (ks << 5) + (lg << 3)) ^ ((row & 7) << 3);
                bf16x8 af = *(const bf16x8*)&As[soff];
                #pragma unroll
                for (int nt = 0; nt < CT; ++nt)
                    acc[mt][nt] = MFMA16(af, bfr[nt], acc[mt][nt]);
            }
            if (DUAL) {
                bf16x8 bfr2[CT];
                #pragma unroll
                for (int nt = 0; nt < CT; ++nt)
                    bfr2[nt] = *(const bf16x8*)(B2f + (((size_t)kk * Mt + ct0 + nt) << 9) + (l << 3));
                #pragma unroll
                for (int mt = 0; mt < 2; ++mt) {
                    int row = m0 + (mt << 4) + lr;
                    int soff = ((row << 6) + (ks << 5) + (lg << 3)) ^ ((row & 7) << 3);
                    bf16x8 af2 = *(const bf16x8*)&As2[soff];
                    #pragma unroll
                    for (int nt = 0; nt < CT; ++nt)
                        acc[mt][nt] = MFMA16(af2, bfr2[nt], acc[mt][nt]);
                }
            }
        }
        __syncthreads();
    }

    float scale = 1.f;
    if (OUTM == 1 || OUTM == 2) scale = scale_ptr[scale_idx];
    const int M = Mt << 4;
    #pragma unroll
    for (int mt = 0; mt < 2; ++mt) {
        #pragma unroll
        for (int nt = 0; nt < CT; ++nt) {
            int col = ((ct0 + nt) << 4) + lr;
            float bv = bias ? bias[col] : 0.f;
            #pragma unroll
            for (int r = 0; r < 4; ++r) {
                int grow = row0 + m0 + (mt << 4) + (lg << 2) + r;
                if (grow >= NN) continue;
                float v = acc[mt][nt][r] + bv;
                if (RELU) v = fmaxf(v, 0.f);
                size_t o = (size_t)grow * M + col;
                if (OUTM == 0) ((u16*)outp)[o] = f2bf(v);
                else if (OUTM == 1) ((float*)outp)[o] = scale * v;
                else if (OUTM == 2) ((float*)outp)[o] += scale * v;
                else ((float*)outp)[o] = v;
            }
        }
    }
}

// ---------------------------------------------------------------------------
// CSR build
// ---------------------------------------------------------------------------
__global__ void k_init(int* counts, float* s1, float* s2) {
    int i = blockIdx.x * 256 + threadIdx.x;
    if (i < NN) counts[i] = 0;
    if (i < 512) { s1[i] = 0.f; s2[i] = 0.f; }
}

__global__ void k_csr_count(const int* __restrict__ EI, int* counts) {
    int e = blockIdx.x * 256 + threadIdx.x;
    if (e < NE) atomicAdd(&counts[EI[NE + e]], 1);
}

__global__ __launch_bounds__(1024) void k_scan(const int* __restrict__ counts,
                                               int* offs, int* cursor) {
    __shared__ int buf[1024];
    int t = threadIdx.x;
    int carry = 0;
    for (int chunk = 0; chunk < (NN + 1023) / 1024; ++chunk) {
        int i = chunk * 1024 + t;
        int v = (i < NN) ? counts[i] : 0;
        buf[t] = v;
        __syncthreads();
        for (int o = 1; o < 1024; o <<= 1) {
            int xv = (t >= o) ? buf[t - o] : 0;
            __syncthreads();
            buf[t] += xv;
            __syncthreads();
        }
        int excl = buf[t] - v;
        if (i < NN) { offs[i] = carry + excl; cursor[i] = carry + excl; }
        carry += buf[1023];
        __syncthreads();
    }
    if (t == 0) offs[NN] = carry;
}

__global__ void k_csr_scatter(const int* __restrict__ EI, int* cursor, int* csrc) {
    int e = blockIdx.x * 256 + threadIdx.x;
    if (e < NE) {
        int d = EI[NE + e];
        int pos = atomicAdd(&cursor[d], 1);
        csrc[pos] = EI[e];
    }
}

// ---------------------------------------------------------------------------
// bf16 neighbor aggregation. WU = channels/2 (u32 words), blockDim = WU.
// MODE 0: mean. MODE 1: self + sum.
// ---------------------------------------------------------------------------
template<int WU, int MODE>
__global__ void k_aggb(const u32* __restrict__ in, u32* __restrict__ out,
                       const int* __restrict__ offs, const int* __restrict__ srcs)
{
    int node = blockIdx.x;
    int c = threadIdx.x;
    int o0 = offs[node], o1 = offs[node + 1];
    float s0 = 0.f, s1 = 0.f;
    for (int j = o0; j < o1; ++j) {
        u32 v = in[(size_t)srcs[j] * WU + c];
        s0 += bf2f((u16)(v & 0xffff));
        s1 += bf2f((u16)(v >> 16));
    }
    if (MODE == 0) {
        int d = o1 - o0;
        float r = 1.f / (float)(d > 0 ? d : 1);
        s0 *= r; s1 *= r;
    } else {
        u32 v = in[(size_t)node * WU + c];
        s0 += bf2f((u16)(v & 0xffff));
        s1 += bf2f((u16)(v >> 16));
    }
    out[(size_t)node * WU + c] = (u32)f2bf(s0) | ((u32)f2bf(s1) << 16);
}

// ---------------------------------------------------------------------------
// GAT (bf16 features)
// ---------------------------------------------------------------------------
__global__ void k_gat1_al(const u16* __restrict__ h, const float* __restrict__ a_s,
                          const float* __restrict__ a_d, float* als, float* ald) {
    int idx = blockIdx.x * 64 + threadIdx.x;
    if (idx >= NN * 8) return;
    int node = idx >> 3, hh = idx & 7;
    float s = 0.f, d = 0.f;
    #pragma unroll
    for (int c = 0; c < 10; ++c) {
        float hv = bf2f(h[node * 80 + hh * 10 + c]);
        s = fmaf(hv, a_s[hh * 10 + c], s);
        d = fmaf(hv, a_d[hh * 10 + c], d);
    }
    als[idx] = s; ald[idx] = d;
}

__global__ __launch_bounds__(128) void k_gat1_attn(
    const u16* __restrict__ h, const float* __restrict__ als,
    const float* __restrict__ ald, const float* __restrict__ bias,
    const int* __restrict__ offs, const int* __restrict__ srcs,
    u16* __restrict__ ha)
{
    int node = blockIdx.x;
    int t = threadIdx.x;
    if (t >= 80) return;
    int hh = t / 10;
    int o0 = offs[node], o1 = offs[node + 1];
    float ad = ald[node * 8 + hh];
    float eself = lrelu(als[node * 8 + hh] + ad);
    float m = eself;
    for (int j = o0; j < o1; ++j)
        m = fmaxf(m, lrelu(als[srcs[j] * 8 + hh] + ad));
    float den = 0.f, num = 0.f;
    {
        float wgt = __expf(eself - m);
        den += wgt; num += wgt * bf2f(h[(size_t)node * 80 + t]);
    }
    for (int j = o0; j < o1; ++j) {
        int sc = srcs[j];
        float wgt = __expf(lrelu(als[sc * 8 + hh] + ad) - m);
        den += wgt; num += wgt * bf2f(h[(size_t)sc * 80 + t]);
    }
    ha[(size_t)node * 80 + t] = f2bf(fmaxf(num / den + bias[t], 0.f));
}

__global__ __launch_bounds__(256) void k_gat2_al(
    const u16* __restrict__ h, const float* __restrict__ a_s,
    const float* __restrict__ a_d, float* als, float* ald)
{
    __shared__ float rs[256], rd[256];
    int node = blockIdx.x, t = threadIdx.x;
    float h0 = bf2f(h[(size_t)node * 512 + t]);
    float h1 = bf2f(h[(size_t)node * 512 + 256 + t]);
    rs[t] = h0 * a_s[t] + h1 * a_s[256 + t];
    rd[t] = h0 * a_d[t] + h1 * a_d[256 + t];
    __syncthreads();
    for (int o = 128; o > 0; o >>= 1) {
        if (t < o) { rs[t] += rs[t + o]; rd[t] += rd[t + o]; }
        __syncthreads();
    }
    if (t == 0) { als[node] = rs[0]; ald[node] = rd[0]; }
}

__global__ __launch_bounds__(256) void k_gat2_attn(
    const u16* __restrict__ h, const float* __restrict__ als,
    const float* __restrict__ ald, const float* __restrict__ bias,
    const int* __restrict__ offs, const int* __restrict__ srcs,
    const float* __restrict__ fusion_w, float* __restrict__ Y)
{
    int node = blockIdx.x;
    int t = threadIdx.x;
    float w2 = fusion_w[2];
    int o0 = offs[node], o1 = offs[node + 1];
    float ad = ald[node];
    float eself = lrelu(als[node] + ad);
    float m = eself;
    for (int j = o0; j < o1; ++j) m = fmaxf(m, lrelu(als[srcs[j]] + ad));
    float den = 0.f, n0 = 0.f, n1 = 0.f;
    {
        float wgt = __expf(eself - m);
        den += wgt;
        n0 += wgt * bf2f(h[(size_t)node * 512 + t]);
        n1 += wgt * bf2f(h[(size_t)node * 512 + 256 + t]);
    }
    for (int j = o0; j < o1; ++j) {
        int sc = srcs[j];
        float wgt = __expf(lrelu(als[sc] + ad) - m);
        den += wgt;
        n0 += wgt * bf2f(h[(size_t)sc * 512 + t]);
        n1 += wgt * bf2f(h[(size_t)sc * 512 + 256 + t]);
    }
    Y[(size_t)node * 512 + t]       += w2 * (n0 / den + bias[t]);
    Y[(size_t)node * 512 + 256 + t] += w2 * (n1 / den + bias[256 + t]);
}

// ---------------------------------------------------------------------------
// BatchNorm + final
// ---------------------------------------------------------------------------
__global__ __launch_bounds__(256) void k_bn_stats(const float* __restrict__ Y,
                                                  float* ssum, float* ssq) {
    int t = threadIdx.x;
    int b = blockIdx.x;
    int r0 = b * 40, r1 = r0 + 40;
    if (r1 > NN) r1 = NN;
    float s0 = 0, s1 = 0, q0 = 0, q1 = 0;
    for (int r = r0; r < r1; ++r) {
        float v0 = Y[(size_t)r * 512 + t];
        float v1 = Y[(size_t)r * 512 + 256 + t];
        s0 += v0; q0 += v0 * v0; s1 += v1; q1 += v1 * v1;
    }
    atomicAdd(&ssum[t], s0); atomicAdd(&ssum[256 + t], s1);
    atomicAdd(&ssq[t], q0);  atomicAdd(&ssq[256 + t], q1);
}

__global__ void k_bn_final(const float* ssum, const float* ssq, float* mu, float* inv) {
    int c = blockIdx.x * 256 + threadIdx.x;
    if (c < 512) {
        float m = ssum[c] / (float)NN;
        float v = ssq[c] / (float)NN - m * m;
        mu[c] = m;
        inv[c] = rsqrtf(v + 1e-5f);
    }
}

__global__ void k_bn_apply(const float* __restrict__ Y, const float* __restrict__ mu,
                           const float* __restrict__ inv, u32* __restrict__ Yb) {
    int i = blockIdx.x * 256 + threadIdx.x;
    if (i >= NN * 256) return;
    int c2 = (i & 255) << 1;
    float2 v = ((const float2*)Y)[i];
    float a = (v.x - mu[c2]) * inv[c2];
    float b = (v.y - mu[c2 + 1]) * inv[c2 + 1];
    Yb[i] = (u32)f2bf(a) | ((u32)f2bf(b) << 16);
}

__global__ __launch_bounds__(256) void k_final(
    const float* __restrict__ y2, const int* __restrict__ EI,
    const int* __restrict__ tid, const float* __restrict__ fcW,
    const float* __restrict__ fcb, float* __restrict__ out)
{
    int pair = blockIdx.x * 4 + (threadIdx.x >> 6);
    int lane = threadIdx.x & 63;
    if (pair >= NT) return;
    int eid = tid[pair];
    int a = EI[eid], b = EI[NE + eid];
    float acc[7] = {};
    for (int c = lane; c < 512; c += 64) {
        float v = y2[(size_t)a * 512 + c] * y2[(size_t)b * 512 + c];
        #pragma unroll
        for (int j = 0; j < 7; ++j) acc[j] = fmaf(v, fcW[c * 7 + j], acc[j]);
    }
    for (int o = 32; o > 0; o >>= 1) {
        #pragma unroll
        for (int j = 0; j < 7; ++j) acc[j] += __shfl_down(acc[j], o);
    }
    if (lane == 0) {
        #pragma unroll
        for (int j = 0; j < 7; ++j) out[(size_t)pair * 7 + j] = acc[j] + fcb[j];
    }
}

// ---------------------------------------------------------------------------
extern "C" void kernel_launch(void* const* d_in, const int* in_sizes, int n_in,
                              void* d_out, int out_size, void* d_ws, size_t ws_size,
                              hipStream_t stream)
{
    (void)in_sizes; (void)n_in; (void)out_size; (void)ws_size;
    const float* x        = (const float*)d_in[0];
    const int*   EI       = (const int*)d_in[1];
    const int*   tid      = (const int*)d_in[2];
    const float* Wp1      = (const float*)d_in[3];
    const float* bp1      = (const float*)d_in[4];
    const float* Wp2      = (const float*)d_in[5];
    const float* bp2      = (const float*)d_in[6];
    const float* Wp3      = (const float*)d_in[7];
    const float* bp3      = (const float*)d_in[8];
    const float* sage1_Wl = (const float*)d_in[9];
    const float* sage1_bl = (const float*)d_in[10];
    const float* sage1_Wr = (const float*)d_in[11];
    const float* sage2_Wl = (const float*)d_in[12];
    const float* sage2_bl = (const float*)d_in[13];
    const float* sage2_Wr = (const float*)d_in[14];
    const float* gin1_W1  = (const float*)d_in[15];
    const float* gin1_b1  = (const float*)d_in[16];
    const float* gin1_W2  = (const float*)d_in[17];
    const float* gin1_b2  = (const float*)d_in[18];
    const float* gin2_W1  = (const float*)d_in[19];
    const float* gin2_b1  = (const float*)d_in[20];
    const float* gin2_W2  = (const float*)d_in[21];
    const float* gin2_b2  = (const float*)d_in[22];
    const float* gin_lin_W= (const float*)d_in[23];
    const float* gin_lin_b= (const float*)d_in[24];
    const float* gat1_W   = (const float*)d_in[25];
    const float* gat1_as  = (const float*)d_in[26];
    const float* gat1_ad  = (const float*)d_in[27];
    const float* gat1_b   = (const float*)d_in[28];
    const float* gat2_W   = (const float*)d_in[29];
    const float* gat2_as  = (const float*)d_in[30];
    const float* gat2_ad  = (const float*)d_in[31];
    const float* gat2_b   = (const float*)d_in[32];
    const float* fusion_w = (const float*)d_in[33];
    const float* lin1_W   = (const float*)d_in[34];
    const float* lin1_b   = (const float*)d_in[35];
    const float* lin2_W   = (const float*)d_in[36];
    const float* lin2_b   = (const float*)d_in[37];
    const float* fc2_W    = (const float*)d_in[38];
    const float* fc2_b    = (const float*)d_in[39];

    char* base = (char*)d_ws;
    // R0 region (41 MB): xb during pointnet; then aliased buffers (disjoint lifetimes)
    u16* xb    = (u16*)base;                       // 40,960,000 B
    u16* mean1 = (u16*)base;                       // [0, 5.12M)
    u16* agg1  = (u16*)(base + 5120000);           // [5.12M,10.24M)
    u16* h2b   = (u16*)base;                       // [0,10.24M)   gat2
    u16* Ybn   = (u16*)(base + 10240000);          // [10.24,20.48M)
    u16* y1b   = (u16*)(base + 20480000);          // [20.48,30.72M)
    float* y2  = (float*)base;                     // [0,20.48M)   after h2/Ybn dead
    size_t off = 40960000;
    u16* featb = (u16*)(base + off); off += 5120000;
    u16* hsb   = (u16*)(base + off); off += 2560000;
    u16* mean2 = (u16*)(base + off); off += 2560000;
    u16* g1    = (u16*)(base + off); off += 2560000;
    u16* g2    = (u16*)(base + off); off += 2560000;
    u16* hgat  = (u16*)(base + off); off += 1600000;
    u16* hab   = (u16*)(base + off); off += 1600000;
    float* Y   = (float*)(base + off); off += 20480000;
    float* als1 = (float*)(base + off); off += 320000;
    float* ald1 = (float*)(base + off); off += 320000;
    float* als2 = (float*)(base + off); off += 40000;
    float* ald2 = (float*)(base + off); off += 40000;
    float* ssum = (float*)(base + off); off += 2048;
    float* ssq  = (float*)(base + off); off += 2048;
    float* mu   = (float*)(base + off); off += 2048;
    float* inv  = (float*)(base + off); off += 2048;
    int* counts = (int*)(base + off); off += 40000;
    int* offs   = (int*)(base + off); off += 40016;
    int* cursor = (int*)(base + off); off += 40000;
    int* csrc   = (int*)(base + off); off += 640000;
    u16* W1f    = (u16*)(base + off); off += 4096;
    u16* W2f    = (u16*)(base + off); off += 16384;
    u16* W3f    = (u16*)(base + off); off += 65536;
    u16* s1lf   = (u16*)(base + off); off += 65536;   // 256x128
    u16* s1rf   = (u16*)(base + off); off += 65536;
    u16* g1w1f  = (u16*)(base + off); off += 65536;   // 256x128
    u16* g1w2f  = (u16*)(base + off); off += 32768;   // 128x128
    u16* ga1f   = (u16*)(base + off); off += 40960;   // 256x80
    u16* s2lf   = (u16*)(base + off); off += 131072;  // 128x512
    u16* s2rf   = (u16*)(base + off); off += 131072;
    u16* g2w1f  = (u16*)(base + off); off += 32768;
    u16* g2w2f  = (u16*)(base + off); off += 32768;
    u16* glinf  = (u16*)(base + off); off += 131072;  // 128x512
    u16* ga2f   = (u16*)(base + off); off += 131072;  // 80(->128)x512
    u16* l1f    = (u16*)(base + off); off += 524288;  // 512x512
    u16* l2f    = (u16*)(base + off); off += 524288;

    k_init<<<40, 256, 0, stream>>>(counts, ssum, ssq);
    k_cvt_x<<<2048, 256, 0, stream>>>(x, (u32*)xb);
    k_wfrag<<<128, 256, 0, stream>>>(Wp1, Wp2, Wp3, W1f, W2f, W3f);
    k_pack<<<256, 256, 0, stream>>>(sage1_Wl, s1lf, 256, 8);
    k_pack<<<256, 256, 0, stream>>>(sage1_Wr, s1rf, 256, 8);
    k_pack<<<256, 256, 0, stream>>>(gin1_W1,  g1w1f, 256, 8);
    k_pack<<<256, 256, 0, stream>>>(gin1_W2,  g1w2f, 128, 8);
    k_pack<<<256, 256, 0, stream>>>(gat1_W,   ga1f, 256, 5);
    k_pack<<<256, 256, 0, stream>>>(sage2_Wl, s2lf, 128, 32);
    k_pack<<<256, 256, 0, stream>>>(sage2_Wr, s2rf, 128, 32);
    k_pack<<<256, 256, 0, stream>>>(gin2_W1,  g2w1f, 128, 8);
    k_pack<<<256, 256, 0, stream>>>(gin2_W2,  g2w2f, 128, 8);
    k_pack<<<256, 256, 0, stream>>>(gin_lin_W, glinf, 128, 32);
    k_pack<<<256, 256, 0, stream>>>(gat2_W,   ga2f, 80, 32);
    k_pack<<<256, 256, 0, stream>>>(lin1_W,   l1f, 512, 32);
    k_pack<<<256, 256, 0, stream>>>(lin2_W,   l2f, 512, 32);

    k_pointnet_mfma<<<NN, 256, 0, stream>>>(xb, W1f, bp1, W2f, bp2, W3f, bp3, featb);
    k_csr_count<<<(NE + 255) / 256, 256, 0, stream>>>(EI, counts);
    k_scan<<<1, 1024, 0, stream>>>(counts, offs, cursor);
    k_csr_scatter<<<(NE + 255) / 256, 256, 0, stream>>>(EI, cursor, csrc);

    dim3 gRows(1, 79), gWide(4, 79);

    // aggregations on feat (bf16)
    k_aggb<128, 0><<<NN, 128, 0, stream>>>((const u32*)featb, (u32*)mean1, offs, csrc);
    k_aggb<128, 1><<<NN, 128, 0, stream>>>((const u32*)featb, (u32*)agg1, offs, csrc);

    // SAGE1: hs = relu(mean1@Wl + feat@Wr + bl)
    k_mm<8,1,1,0><<<gRows, 256, 0, stream>>>(mean1, featb, s1lf, s1rf, sage1_bl,
                                             256, 8, hsb, nullptr, 0);
    // GIN1
    k_mm<8,0,1,0><<<gRows, 256, 0, stream>>>(agg1, nullptr, g1w1f, nullptr, gin1_b1,
                                             256, 8, g1, nullptr, 0);
    k_mm<8,0,1,0><<<gRows, 256, 0, stream>>>(g1, nullptr, g1w2f, nullptr, gin1_b2,
                                             128, 8, g2, nullptr, 0);
    // GAT1
    k_mm<5,0,0,0><<<gRows, 256, 0, stream>>>(featb, nullptr, ga1f, nullptr, nullptr,
                                             256, 5, hgat, nullptr, 0);
    k_gat1_al<<<1250, 64, 0, stream>>>(hgat, gat1_as, gat1_ad, als1, ald1);
    k_gat1_attn<<<NN, 128, 0, stream>>>(hgat, als1, ald1, gat1_b, offs, csrc, hab);

    // SAGE2: Y = w0*(mean2@Wl + hs@Wr + bl)
    k_aggb<64, 0><<<NN, 64, 0, stream>>>((const u32*)hsb, (u32*)mean2, offs, csrc);
    k_mm<8,1,0,1><<<gWide, 256, 0, stream>>>(mean2, hsb, s2lf, s2rf, sage2_bl,
                                             128, 32, Y, fusion_w, 0);
    // GIN2
    k_aggb<64, 1><<<NN, 64, 0, stream>>>((const u32*)g2, (u32*)g1, offs, csrc);
    k_mm<8,0,1,0><<<gRows, 256, 0, stream>>>(g1, nullptr, g2w1f, nullptr, gin2_b1,
                                             128, 8, g2, nullptr, 0);
    k_mm<8,0,1,0><<<gRows, 256, 0, stream>>>(g2, nullptr, g2w2f, nullptr, gin2_b2,
                                             128, 8, g1, nullptr, 0);
    k_mm<8,0,0,2><<<gWide, 256, 0, stream>>>(g1, nullptr, glinf, nullptr, gin_lin_b,
                                             128, 32, Y, fusion_w, 1);
    // GAT2
    k_mm<8,0,0,0><<<gWide, 256, 0, stream>>>(hab, nullptr, ga2f, nullptr, nullptr,
                                             80, 32, h2b, nullptr, 0);
    k_gat2_al<<<NN, 256, 0, stream>>>(h2b, gat2_as, gat2_ad, als2, ald2);
    k_gat2_attn<<<NN, 256, 0, stream>>>(h2b, als2, ald2, gat2_b, offs, csrc, fusion_w, Y);

    // BN + head
    k_bn_stats<<<250, 256, 0, stream>>>(Y, ssum, ssq);
    k_bn_final<<<2, 256, 0, stream>>>(ssum, ssq, mu, inv);
    k_bn_apply<<<10000, 256, 0, stream>>>(Y, mu, inv, (u32*)Ybn);
    k_mm<8,0,1,0><<<gWide, 256, 0, stream>>>(Ybn, nullptr, l1f, nullptr, lin1_b,
                                             512, 32, y1b, nullptr, 0);
    k_mm<8,0,0,3><<<gWide, 256, 0, stream>>>(y1b, nullptr, l2f, nullptr, lin2_b,
                                             512, 32, y2, nullptr, 0);

    k_final<<<(NT + 3) / 4, 256, 0, stream>>>(y2, EI, tid, fc2_W, fc2_b, (float*)d_out);
}

// Round 6
// 616.026 us; speedup vs baseline: 6.4789x; 1.1904x over previous
//
#include <hip/hip_runtime.h>
#include <math.h>

#define NN 10000
#define NE 160000
#define NT 50000

typedef unsigned short u16;
typedef unsigned int u32;
typedef __attribute__((ext_vector_type(8))) short bf16x8;
typedef __attribute__((ext_vector_type(4))) float f32x4;

__device__ __forceinline__ float bf2f(u16 u) { return __uint_as_float(((u32)u) << 16); }
__device__ __forceinline__ u16 f2bf(float f) {
    u32 x = __float_as_uint(f);
    return (u16)((x + 0x7fffu + ((x >> 16) & 1u)) >> 16);
}
// HW packed f32->bf16 (RNE), 1 VALU op per 2 values. No builtin on gfx950; inline asm.
__device__ __forceinline__ u32 cvtpk(float a, float b) {
    u32 r;
    asm("v_cvt_pk_bf16_f32 %0, %1, %2" : "=v"(r) : "v"(a), "v"(b));
    return r;
}
__device__ __forceinline__ float lrelu(float x) { return x > 0.f ? x : 0.2f * x; }

#define MFMA16(a, b, c) __builtin_amdgcn_mfma_f32_16x16x32_bf16((a), (b), (c), 0, 0, 0)

// ---------------------------------------------------------------------------
// Prep: convert x to bf16
// ---------------------------------------------------------------------------
__global__ void k_cvt_x(const float* __restrict__ x, u32* __restrict__ xb) {
    const int total = NN * 128 * 8;
    for (int i = blockIdx.x * 256 + threadIdx.x; i < total; i += gridDim.x * 256) {
        float2 v = ((const float2*)x)[i];
        xb[i] = cvtpk(v.x, v.y);
    }
}

// ---------------------------------------------------------------------------
// Prep: pack pointnet W1/W2/W3 into MFMA B-fragment order
// ---------------------------------------------------------------------------
__global__ void k_wfrag(const float* __restrict__ W1, const float* __restrict__ W2,
                        const float* __restrict__ W3,
                        u16* __restrict__ W1f, u16* __restrict__ W2f, u16* __restrict__ W3f) {
    int i = blockIdx.x * 256 + threadIdx.x;
    if (i < 2048) {
        int e = i & 7, l = (i >> 3) & 63, nt = i >> 9;
        int k = (l >> 4) * 8 + e, c = nt * 16 + (l & 15);
        W1f[i] = (k < 16) ? f2bf(W1[k * 64 + c]) : (u16)0;
    }
    if (i < 8192) {
        int e = i & 7, l = (i >> 3) & 63, nt = (i >> 9) & 7, ks = i >> 12;
        int k = ks * 32 + (l >> 4) * 8 + e, c = nt * 16 + (l & 15);
        W2f[i] = f2bf(W2[k * 128 + c]);
    }
    if (i < 32768) {
        int e = i & 7, l = (i >> 3) & 63, nt = (i >> 9) & 15, ks = i >> 13;
        int k = ks * 32 + (l >> 4) * 8 + e, c = nt * 16 + (l & 15);
        W3f[i] = f2bf(W3[k * 256 + c]);
    }
}

// ---------------------------------------------------------------------------
// Generic weight pack: fp32 [K x M] -> bf16 frag order [ceil64(K)/32][M/16][64][8]
// ---------------------------------------------------------------------------
__global__ void k_pack(const float* __restrict__ W, u16* __restrict__ Wf, int K, int Mt) {
    int total = (((K + 63) & ~63) >> 5) * Mt * 512;
    for (int i = blockIdx.x * 256 + threadIdx.x; i < total; i += gridDim.x * 256) {
        int e = i & 7, l = (i >> 3) & 63, mt = (i >> 9) % Mt, kk = i / (Mt << 9);
        int k = (kk << 5) + ((l >> 4) << 3) + e;
        int c = (mt << 4) + (l & 15);
        Wf[i] = (k < K) ? f2bf(W[(size_t)k * (Mt << 4) + c]) : (u16)0;
    }
}

// ---------------------------------------------------------------------------
// MFMA point-net. 32KB LDS (h1 aliases h2's first 16KB; layer-2 A-frags are
// wave-local so they're preloaded to regs, then h2 overwrites h1 after barrier).
// Bias folded into MFMA C-init. cvt_pk for all bf16 conversion.
// ---------------------------------------------------------------------------
__global__ __launch_bounds__(256) void k_pointnet_mfma(
    const u16* __restrict__ xb,
    const u16* __restrict__ W1f, const float* __restrict__ b1,
    const u16* __restrict__ W2f, const float* __restrict__ b2,
    const u16* __restrict__ W3f, const float* __restrict__ b3,
    u16* __restrict__ featb)
{
    __shared__ u16 buf[16384];   // 32 KB: h1 = buf[0..8192), h2 = buf[0..16384)

    const int node = blockIdx.x;
    const int t = threadIdx.x;
    const int w = t >> 6;
    const int l = t & 63;
    const int lr = l & 15;
    const int lg = l >> 4;

    // ---------------- layer 1: rows w*32..+31 -> h1 (buf[0..8192)) ----------
    {
        bf16x8 a0 = {0,0,0,0,0,0,0,0}, a1 = a0;
        if (lg < 2) {
            const u16* px = xb + ((size_t)node * 128 + w * 32 + lr) * 16 + lg * 8;
            a0 = *(const bf16x8*)px;
            a1 = *(const bf16x8*)(px + 256);
        }
        f32x4 acc[2][4];
        #pragma unroll
        for (int nt = 0; nt < 4; ++nt) {
            float bv = b1[nt * 16 + lr];
            f32x4 ci = {bv, bv, bv, bv};
            bf16x8 bf_ = *(const bf16x8*)(W1f + (nt * 64 + l) * 8);
            acc[0][nt] = MFMA16(a0, bf_, ci);
            acc[1][nt] = MFMA16(a1, bf_, ci);
        }
        #pragma unroll
        for (int mt = 0; mt < 2; ++mt) {
            #pragma unroll
            for (int nt = 0; nt < 4; ++nt) {
                int col = nt * 16 + lr;
                int r0 = w * 32 + mt * 16 + lg * 4;
                u32 p01 = cvtpk(fmaxf(acc[mt][nt][0], 0.f), fmaxf(acc[mt][nt][1], 0.f));
                u32 p23 = cvtpk(fmaxf(acc[mt][nt][2], 0.f), fmaxf(acc[mt][nt][3], 0.f));
                buf[((r0    ) * 64 + col) ^ (((r0    ) & 7) << 3)] = (u16)p01;
                buf[((r0 + 1) * 64 + col) ^ (((r0 + 1) & 7) << 3)] = (u16)(p01 >> 16);
                buf[((r0 + 2) * 64 + col) ^ (((r0 + 2) & 7) << 3)] = (u16)p23;
                buf[((r0 + 3) * 64 + col) ^ (((r0 + 3) & 7) << 3)] = (u16)(p23 >> 16);
            }
        }
    }
    // no barrier needed: wave w only reads its OWN h1 rows below (in-wave LDS order)

    // ---------------- layer 2: preload own A-frags, barrier, write h2 -------
    {
        bf16x8 af[2][2];
        #pragma unroll
        for (int mt = 0; mt < 2; ++mt) {
            #pragma unroll
            for (int ks = 0; ks < 2; ++ks) {
                int row = w * 32 + mt * 16 + lr;
                int elem = row * 64 + ks * 32 + lg * 8;
                af[mt][ks] = *(const bf16x8*)&buf[elem ^ ((row & 7) << 3)];
            }
        }
        __syncthreads();   // all h1 reads complete before h2 writes clobber it

        f32x4 acc2[2][8];
        #pragma unroll
        for (int nt = 0; nt < 8; ++nt) {
            float bv = b2[nt * 16 + lr];
            f32x4 ci = {bv, bv, bv, bv};
            acc2[0][nt] = ci;
            acc2[1][nt] = ci;
        }
        #pragma unroll
        for (int ks = 0; ks < 2; ++ks) {
            #pragma unroll
            for (int nt = 0; nt < 8; ++nt) {
                bf16x8 bf_ = *(const bf16x8*)(W2f + ((ks * 8 + nt) * 64 + l) * 8);
                acc2[0][nt] = MFMA16(af[0][ks], bf_, acc2[0][nt]);
                acc2[1][nt] = MFMA16(af[1][ks], bf_, acc2[1][nt]);
            }
        }
        #pragma unroll
        for (int mt = 0; mt < 2; ++mt) {
            #pragma unroll
            for (int nt = 0; nt < 8; ++nt) {
                int col = nt * 16 + lr;
                int r0 = w * 32 + mt * 16 + lg * 4;
                u32 p01 = cvtpk(fmaxf(acc2[mt][nt][0], 0.f), fmaxf(acc2[mt][nt][1], 0.f));
                u32 p23 = cvtpk(fmaxf(acc2[mt][nt][2], 0.f), fmaxf(acc2[mt][nt][3], 0.f));
                buf[((r0    ) * 128 + col) ^ (((r0    ) & 7) << 3)] = (u16)p01;
                buf[((r0 + 1) * 128 + col) ^ (((r0 + 1) & 7) << 3)] = (u16)(p01 >> 16);
                buf[((r0 + 2) * 128 + col) ^ (((r0 + 2) & 7) << 3)] = (u16)p23;
                buf[((r0 + 3) * 128 + col) ^ (((r0 + 3) & 7) << 3)] = (u16)(p23 >> 16);
            }
        }
    }
    __syncthreads();

    // ---------------- layer 3: cols w*64..+63, max-pool over 128 rows -------
    {
        float pmax[4] = {0.f, 0.f, 0.f, 0.f};   // pmax>=0 subsumes relu
        #pragma unroll
        for (int half = 0; half < 2; ++half) {
            f32x4 acc3[4][4];
            #pragma unroll
            for (int nt = 0; nt < 4; ++nt) {
                float bv = b3[w * 64 + nt * 16 + lr];
                f32x4 ci = {bv, bv, bv, bv};
                #pragma unroll
                for (int mt = 0; mt < 4; ++mt) acc3[mt][nt] = ci;
            }
            #pragma unroll
            for (int ks = 0; ks < 4; ++ks) {
                bf16x8 bf_[4];
                #pragma unroll
                for (int nt = 0; nt < 4; ++nt)
                    bf_[nt] = *(const bf16x8*)(W3f + ((ks * 16 + w * 4 + nt) * 64 + l) * 8);
                #pragma unroll
                for (int mt = 0; mt < 4; ++mt) {
                    int row = half * 64 + mt * 16 + lr;
                    int elem = row * 128 + ks * 32 + lg * 8;
                    bf16x8 af = *(const bf16x8*)&buf[elem ^ ((row & 7) << 3)];
                    #pragma unroll
                    for (int nt = 0; nt < 4; ++nt)
                        acc3[mt][nt] = MFMA16(af, bf_[nt], acc3[mt][nt]);
                }
            }
            #pragma unroll
            for (int nt = 0; nt < 4; ++nt) {
                #pragma unroll
                for (int mt = 0; mt < 4; ++mt) {
                    pmax[nt] = fmaxf(fmaxf(pmax[nt], acc3[mt][nt][0]),
                                     fmaxf(acc3[mt][nt][1],
                                           fmaxf(acc3[mt][nt][2], acc3[mt][nt][3])));
                }
            }
        }
        #pragma unroll
        for (int nt = 0; nt < 4; ++nt) {
            pmax[nt] = fmaxf(pmax[nt], __shfl_xor(pmax[nt], 16));
            pmax[nt] = fmaxf(pmax[nt], __shfl_xor(pmax[nt], 32));
        }
        if (l < 16) {
            #pragma unroll
            for (int nt = 0; nt < 4; ++nt)
                featb[(size_t)node * 256 + w * 64 + nt * 16 + l] = f2bf(pmax[nt]);
        }
    }
}

// ---------------------------------------------------------------------------
// Generic bf16 MFMA GEMM. A: [N x K] bf16 row-major (or fp32 if NORMA, with
// (A-mu)*inv applied during staging); Bf packed frag order.
// 128-row block, BK=64, 4 waves split M, CT col-tiles of 16. Bias in C-init.
// OUTM: 0 bf16 out; 1 fp32 = scale*v; 2 fp32 += scale*v; 3 fp32 out.
// NOTE: template params must NOT be named NT (macro collision).
// ---------------------------------------------------------------------------
template<int CT, int DUAL, int RELU, int OUTM, int NORMA>
__global__ __launch_bounds__(256) void k_mm(
    const u16* __restrict__ A, const u16* __restrict__ A2,
    const u16* __restrict__ Bf, const u16* __restrict__ B2f,
    const float* __restrict__ bias, int K, int Mt,
    void* __restrict__ outp,
    const float* __restrict__ scale_ptr, int scale_idx,
    const float* __restrict__ mu, const float* __restrict__ inv)
{
    __shared__ u16 As[8192];
    __shared__ u16 As2[DUAL ? 8192 : 8];

    const int t = threadIdx.x;
    const int l = t & 63, lr = l & 15, lg = l >> 4;
    const int row0 = blockIdx.y << 7;
    const int ct0 = blockIdx.x * CT;
    const int m0 = (t >> 6) << 5;

    f32x4 acc[2][CT];
    #pragma unroll
    for (int nt = 0; nt < CT; ++nt) {
        float bv = bias ? bias[((ct0 + nt) << 4) + lr] : 0.f;
        f32x4 ci = {bv, bv, bv, bv};
        acc[0][nt] = ci;
        acc[1][nt] = ci;
    }

    const int KS = (K + 63) >> 6;
    for (int kblk = 0; kblk < KS; ++kblk) {
        const int k0 = kblk << 6;
        if (kblk) __syncthreads();
        #pragma unroll
        for (int j = 0; j < 4; ++j) {
            int si = t + (j << 8);
            int row = si >> 3, seg = si & 7;
            int gr = row0 + row;
            int kb = k0 + (seg << 3);
            int soff = ((row << 6) + (seg << 3)) ^ ((row & 7) << 3);
            if (NORMA) {
                u32 q0 = 0, q1 = 0, q2 = 0, q3 = 0;
                if (gr < NN) {
                    const float* Af = (const float*)A;
                    float4 f0 = *(const float4*)(Af + (size_t)gr * K + kb);
                    float4 f1 = *(const float4*)(Af + (size_t)gr * K + kb + 4);
                    q0 = cvtpk((f0.x - mu[kb+0]) * inv[kb+0], (f0.y - mu[kb+1]) * inv[kb+1]);
                    q1 = cvtpk((f0.z - mu[kb+2]) * inv[kb+2], (f0.w - mu[kb+3]) * inv[kb+3]);
                    q2 = cvtpk((f1.x - mu[kb+4]) * inv[kb+4], (f1.y - mu[kb+5]) * inv[kb+5]);
                    q3 = cvtpk((f1.z - mu[kb+6]) * inv[kb+6], (f1.w - mu[kb+7]) * inv[kb+7]);
                }
                u32* dst = (u32*)&As[soff];
                dst[0] = q0; dst[1] = q1; dst[2] = q2; dst[3] = q3;
            } else {
                bf16x8 v = {0,0,0,0,0,0,0,0};
                bf16x8 v2 = {0,0,0,0,0,0,0,0};
                if (gr < NN) {
                    if (kb + 8 <= K) {
                        v = *(const bf16x8*)(A + (size_t)gr * K + kb);
                        if (DUAL) v2 = *(const bf16x8*)(A2 + (size_t)gr * K + kb);
                    } else {
                        #pragma unroll
                        for (int e = 0; e < 8; ++e) if (kb + e < K) {
                            v[e] = (short)A[(size_t)gr * K + kb + e];
                            if (DUAL) v2[e] = (short)A2[(size_t)gr * K + kb + e];
                        }
                    }
                }
                *(bf16x8*)&As[soff] = v;
                if (DUAL) *(bf16x8*)&As2[soff] = v2;
            }
        }
        __syncthreads();
        #pragma unroll
        for (int ks = 0; ks < 2; ++ks) {
            const int kk = (k0 >> 5) + ks;
            bf16x8 bfr[CT];
            #pragma unroll
            for (int nt = 0; nt < CT; ++nt)
                bfr[nt] = *(const bf16x8*)(Bf + (((size_t)kk * Mt + ct0 + nt) << 9) + (l << 3));
            #pragma unroll
            for (int mt = 0; mt < 2; ++mt) {
                int row = m0 + (mt << 4) + lr;
                int soff = ((row << 6) + (ks << 5) + (lg << 3)) ^ ((row & 7) << 3);
                bf16x8 af = *(const bf16x8*)&As[soff];
                #pragma unroll
                for (int nt = 0; nt < CT; ++nt)
                    acc[mt][nt] = MFMA16(af, bfr[nt], acc[mt][nt]);
            }
            if (DUAL) {
                bf16x8 bfr2[CT];
                #pragma unroll
                for (int nt = 0; nt < CT; ++nt)
                    bfr2[nt] = *(const bf16x8*)(B2f + (((size_t)kk * Mt + ct0 + nt) << 9) + (l << 3));
                #pragma unroll
                for (int mt = 0; mt < 2; ++mt) {
                    int row = m0 + (mt << 4) + lr;
                    int soff = ((row << 6) + (ks << 5) + (lg << 3)) ^ ((row & 7) << 3);
                    bf16x8 af2 = *(const bf16x8*)&As2[soff];
                    #pragma unroll
                    for (int nt = 0; nt < CT; ++nt)
                        acc[mt][nt] = MFMA16(af2, bfr2[nt], acc[mt][nt]);
                }
            }
        }
    }

    float scale = 1.f;
    if (OUTM == 1 || OUTM == 2) scale = scale_ptr[scale_idx];
    const int M = Mt << 4;
    #pragma unroll
    for (int mt = 0; mt < 2; ++mt) {
        #pragma unroll
        for (int nt = 0; nt < CT; ++nt) {
            int col = ((ct0 + nt) << 4) + lr;
            #pragma unroll
            for (int r = 0; r < 4; ++r) {
                int grow = row0 + m0 + (mt << 4) + (lg << 2) + r;
                if (grow >= NN) continue;
                float v = acc[mt][nt][r];
                if (RELU) v = fmaxf(v, 0.f);
                size_t o = (size_t)grow * M + col;
                if (OUTM == 0) ((u16*)outp)[o] = f2bf(v);
                else if (OUTM == 1) ((float*)outp)[o] = scale * v;
                else if (OUTM == 2) ((float*)outp)[o] += scale * v;
                else ((float*)outp)[o] = v;
            }
        }
    }
}

// ---------------------------------------------------------------------------
// CSR build
// ---------------------------------------------------------------------------
__global__ void k_init(int* counts, float* s1, float* s2) {
    int i = blockIdx.x * 256 + threadIdx.x;
    if (i < NN) counts[i] = 0;
    if (i < 512) { s1[i] = 0.f; s2[i] = 0.f; }
}

__global__ void k_csr_count(const int* __restrict__ EI, int* counts) {
    int e = blockIdx.x * 256 + threadIdx.x;
    if (e < NE) atomicAdd(&counts[EI[NE + e]], 1);
}

__global__ __launch_bounds__(1024) void k_scan(const int* __restrict__ counts,
                                               int* offs, int* cursor) {
    __shared__ int buf[1024];
    int t = threadIdx.x;
    int carry = 0;
    for (int chunk = 0; chunk < (NN + 1023) / 1024; ++chunk) {
        int i = chunk * 1024 + t;
        int v = (i < NN) ? counts[i] : 0;
        buf[t] = v;
        __syncthreads();
        for (int o = 1; o < 1024; o <<= 1) {
            int xv = (t >= o) ? buf[t - o] : 0;
            __syncthreads();
            buf[t] += xv;
            __syncthreads();
        }
        int excl = buf[t] - v;
        if (i < NN) { offs[i] = carry + excl; cursor[i] = carry + excl; }
        carry += buf[1023];
        __syncthreads();
    }
    if (t == 0) offs[NN] = carry;
}

__global__ void k_csr_scatter(const int* __restrict__ EI, int* cursor, int* csrc) {
    int e = blockIdx.x * 256 + threadIdx.x;
    if (e < NE) {
        int d = EI[NE + e];
        int pos = atomicAdd(&cursor[d], 1);
        csrc[pos] = EI[e];
    }
}

// ---------------------------------------------------------------------------
// bf16 neighbor aggregation. WU = channels/2 (u32 words), blockDim = WU.
// MODE 0: mean. MODE 1: self + sum.
// ---------------------------------------------------------------------------
template<int WU, int MODE>
__global__ void k_aggb(const u32* __restrict__ in, u32* __restrict__ out,
                       const int* __restrict__ offs, const int* __restrict__ srcs)
{
    int node = blockIdx.x;
    int c = threadIdx.x;
    int o0 = offs[node], o1 = offs[node + 1];
    float s0 = 0.f, s1 = 0.f;
    for (int j = o0; j < o1; ++j) {
        u32 v = in[(size_t)srcs[j] * WU + c];
        s0 += bf2f((u16)(v & 0xffff));
        s1 += bf2f((u16)(v >> 16));
    }
    if (MODE == 0) {
        int d = o1 - o0;
        float r = 1.f / (float)(d > 0 ? d : 1);
        s0 *= r; s1 *= r;
    } else {
        u32 v = in[(size_t)node * WU + c];
        s0 += bf2f((u16)(v & 0xffff));
        s1 += bf2f((u16)(v >> 16));
    }
    out[(size_t)node * WU + c] = cvtpk(s0, s1);
}

// ---------------------------------------------------------------------------
// GAT (bf16 features)
// ---------------------------------------------------------------------------
__global__ void k_gat1_al(const u16* __restrict__ h, const float* __restrict__ a_s,
                          const float* __restrict__ a_d, float* als, float* ald) {
    int idx = blockIdx.x * 64 + threadIdx.x;
    if (idx >= NN * 8) return;
    int node = idx >> 3, hh = idx & 7;
    float s = 0.f, d = 0.f;
    #pragma unroll
    for (int c = 0; c < 10; ++c) {
        float hv = bf2f(h[node * 80 + hh * 10 + c]);
        s = fmaf(hv, a_s[hh * 10 + c], s);
        d = fmaf(hv, a_d[hh * 10 + c], d);
    }
    als[idx] = s; ald[idx] = d;
}

__global__ __launch_bounds__(128) void k_gat1_attn(
    const u16* __restrict__ h, const float* __restrict__ als,
    const float* __restrict__ ald, const float* __restrict__ bias,
    const int* __restrict__ offs, const int* __restrict__ srcs,
    u16* __restrict__ ha)
{
    int node = blockIdx.x;
    int t = threadIdx.x;
    if (t >= 80) return;
    int hh = t / 10;
    int o0 = offs[node], o1 = offs[node + 1];
    float ad = ald[node * 8 + hh];
    float eself = lrelu(als[node * 8 + hh] + ad);
    float m = eself;
    for (int j = o0; j < o1; ++j)
        m = fmaxf(m, lrelu(als[srcs[j] * 8 + hh] + ad));
    float den = 0.f, num = 0.f;
    {
        float wgt = __expf(eself - m);
        den += wgt; num += wgt * bf2f(h[(size_t)node * 80 + t]);
    }
    for (int j = o0; j < o1; ++j) {
        int sc = srcs[j];
        float wgt = __expf(lrelu(als[sc * 8 + hh] + ad) - m);
        den += wgt; num += wgt * bf2f(h[(size_t)sc * 80 + t]);
    }
    ha[(size_t)node * 80 + t] = f2bf(fmaxf(num / den + bias[t], 0.f));
}

__global__ __launch_bounds__(256) void k_gat2_al(
    const u16* __restrict__ h, const float* __restrict__ a_s,
    const float* __restrict__ a_d, float* als, float* ald)
{
    __shared__ float rs[256], rd[256];
    int node = blockIdx.x, t = threadIdx.x;
    float h0 = bf2f(h[(size_t)node * 512 + t]);
    float h1 = bf2f(h[(size_t)node * 512 + 256 + t]);
    rs[t] = h0 * a_s[t] + h1 * a_s[256 + t];
    rd[t] = h0 * a_d[t] + h1 * a_d[256 + t];
    __syncthreads();
    for (int o = 128; o > 0; o >>= 1) {
        if (t < o) { rs[t] += rs[t + o]; rd[t] += rd[t + o]; }
        __syncthreads();
    }
    if (t == 0) { als[node] = rs[0]; ald[node] = rd[0]; }
}

__global__ __launch_bounds__(256) void k_gat2_attn(
    const u16* __restrict__ h, const float* __restrict__ als,
    const float* __restrict__ ald, const float* __restrict__ bias,
    const int* __restrict__ offs, const int* __restrict__ srcs,
    const float* __restrict__ fusion_w, float* __restrict__ Y)
{
    int node = blockIdx.x;
    int t = threadIdx.x;
    float w2 = fusion_w[2];
    int o0 = offs[node], o1 = offs[node + 1];
    float ad = ald[node];
    float eself = lrelu(als[node] + ad);
    float m = eself;
    for (int j = o0; j < o1; ++j) m = fmaxf(m, lrelu(als[srcs[j]] + ad));
    float den = 0.f, n0 = 0.f, n1 = 0.f;
    {
        float wgt = __expf(eself - m);
        den += wgt;
        n0 += wgt * bf2f(h[(size_t)node * 512 + t]);
        n1 += wgt * bf2f(h[(size_t)node * 512 + 256 + t]);
    }
    for (int j = o0; j < o1; ++j) {
        int sc = srcs[j];
        float wgt = __expf(lrelu(als[sc] + ad) - m);
        den += wgt;
        n0 += wgt * bf2f(h[(size_t)sc * 512 + t]);
        n1 += wgt * bf2f(h[(size_t)sc * 512 + 256 + t]);
    }
    Y[(size_t)node * 512 + t]       += w2 * (n0 / den + bias[t]);
    Y[(size_t)node * 512 + 256 + t] += w2 * (n1 / den + bias[256 + t]);
}

// ---------------------------------------------------------------------------
// BatchNorm + final
// ---------------------------------------------------------------------------
__global__ __launch_bounds__(256) void k_bn_stats(const float* __restrict__ Y,
                                                  float* ssum, float* ssq) {
    int t = threadIdx.x;
    int b = blockIdx.x;
    int r0 = b * 40, r1 = r0 + 40;
    if (r1 > NN) r1 = NN;
    float s0 = 0, s1 = 0, q0 = 0, q1 = 0;
    for (int r = r0; r < r1; ++r) {
        float v0 = Y[(size_t)r * 512 + t];
        float v1 = Y[(size_t)r * 512 + 256 + t];
        s0 += v0; q0 += v0 * v0; s1 += v1; q1 += v1 * v1;
    }
    atomicAdd(&ssum[t], s0); atomicAdd(&ssum[256 + t], s1);
    atomicAdd(&ssq[t], q0);  atomicAdd(&ssq[256 + t], q1);
}

__global__ void k_bn_final(const float* ssum, const float* ssq, float* mu, float* inv) {
    int c = blockIdx.x * 256 + threadIdx.x;
    if (c < 512) {
        float m = ssum[c] / (float)NN;
        float v = ssq[c] / (float)NN - m * m;
        mu[c] = m;
        inv[c] = rsqrtf(v + 1e-5f);
    }
}

__global__ __launch_bounds__(256) void k_final(
    const float* __restrict__ y2, const int* __restrict__ EI,
    const int* __restrict__ tid, const float* __restrict__ fcW,
    const float* __restrict__ fcb, float* __restrict__ out)
{
    int pair = blockIdx.x * 4 + (threadIdx.x >> 6);
    int lane = threadIdx.x & 63;
    if (pair >= NT) return;
    int eid = tid[pair];
    int a = EI[eid], b = EI[NE + eid];
    float acc[7] = {};
    for (int c = lane; c < 512; c += 64) {
        float v = y2[(size_t)a * 512 + c] * y2[(size_t)b * 512 + c];
        #pragma unroll
        for (int j = 0; j < 7; ++j) acc[j] = fmaf(v, fcW[c * 7 + j], acc[j]);
    }
    for (int o = 32; o > 0; o >>= 1) {
        #pragma unroll
        for (int j = 0; j < 7; ++j) acc[j] += __shfl_down(acc[j], o);
    }
    if (lane == 0) {
        #pragma unroll
        for (int j = 0; j < 7; ++j) out[(size_t)pair * 7 + j] = acc[j] + fcb[j];
    }
}

// ---------------------------------------------------------------------------
extern "C" void kernel_launch(void* const* d_in, const int* in_sizes, int n_in,
                              void* d_out, int out_size, void* d_ws, size_t ws_size,
                              hipStream_t stream)
{
    (void)in_sizes; (void)n_in; (void)out_size; (void)ws_size;
    const float* x        = (const float*)d_in[0];
    const int*   EI       = (const int*)d_in[1];
    const int*   tid      = (const int*)d_in[2];
    const float* Wp1      = (const float*)d_in[3];
    const float* bp1      = (const float*)d_in[4];
    const float* Wp2      = (const float*)d_in[5];
    const float* bp2      = (const float*)d_in[6];
    const float* Wp3      = (const float*)d_in[7];
    const float* bp3      = (const float*)d_in[8];
    const float* sage1_Wl = (const float*)d_in[9];
    const float* sage1_bl = (const float*)d_in[10];
    const float* sage1_Wr = (const float*)d_in[11];
    const float* sage2_Wl = (const float*)d_in[12];
    const float* sage2_bl = (const float*)d_in[13];
    const float* sage2_Wr = (const float*)d_in[14];
    const float* gin1_W1  = (const float*)d_in[15];
    const float* gin1_b1  = (const float*)d_in[16];
    const float* gin1_W2  = (const float*)d_in[17];
    const float* gin1_b2  = (const float*)d_in[18];
    const float* gin2_W1  = (const float*)d_in[19];
    const float* gin2_b1  = (const float*)d_in[20];
    const float* gin2_W2  = (const float*)d_in[21];
    const float* gin2_b2  = (const float*)d_in[22];
    const float* gin_lin_W= (const float*)d_in[23];
    const float* gin_lin_b= (const float*)d_in[24];
    const float* gat1_W   = (const float*)d_in[25];
    const float* gat1_as  = (const float*)d_in[26];
    const float* gat1_ad  = (const float*)d_in[27];
    const float* gat1_b   = (const float*)d_in[28];
    const float* gat2_W   = (const float*)d_in[29];
    const float* gat2_as  = (const float*)d_in[30];
    const float* gat2_ad  = (const float*)d_in[31];
    const float* gat2_b   = (const float*)d_in[32];
    const float* fusion_w = (const float*)d_in[33];
    const float* lin1_W   = (const float*)d_in[34];
    const float* lin1_b   = (const float*)d_in[35];
    const float* lin2_W   = (const float*)d_in[36];
    const float* lin2_b   = (const float*)d_in[37];
    const float* fc2_W    = (const float*)d_in[38];
    const float* fc2_b    = (const float*)d_in[39];

    char* base = (char*)d_ws;
    // R0 region (41 MB): xb during pointnet; then aliased buffers (disjoint lifetimes)
    u16* xb    = (u16*)base;                       // 40,960,000 B
    u16* mean1 = (u16*)base;                       // [0, 5.12M)
    u16* agg1  = (u16*)(base + 5120000);           // [5.12M,10.24M)
    u16* h2b   = (u16*)base;                       // [0,10.24M)   gat2
    u16* y1b   = (u16*)(base + 20480000);          // [20.48,30.72M)
    float* y2  = (float*)base;                     // [0,20.48M)   after h2b dead
    size_t off = 40960000;
    u16* featb = (u16*)(base + off); off += 5120000;
    u16* hsb   = (u16*)(base + off); off += 2560000;
    u16* mean2 = (u16*)(base + off); off += 2560000;
    u16* g1    = (u16*)(base + off); off += 2560000;
    u16* g2    = (u16*)(base + off); off += 2560000;
    u16* hgat  = (u16*)(base + off); off += 1600000;
    u16* hab   = (u16*)(base + off); off += 1600000;
    float* Y   = (float*)(base + off); off += 20480000;
    float* als1 = (float*)(base + off); off += 320000;
    float* ald1 = (float*)(base + off); off += 320000;
    float* als2 = (float*)(base + off); off += 40000;
    float* ald2 = (float*)(base + off); off += 40000;
    float* ssum = (float*)(base + off); off += 2048;
    float* ssq  = (float*)(base + off); off += 2048;
    float* mu   = (float*)(base + off); off += 2048;
    float* inv  = (float*)(base + off); off += 2048;
    int* counts = (int*)(base + off); off += 40000;
    int* offs   = (int*)(base + off); off += 40016;
    int* cursor = (int*)(base + off); off += 40000;
    int* csrc   = (int*)(base + off); off += 640000;
    u16* W1f    = (u16*)(base + off); off += 4096;
    u16* W2f    = (u16*)(base + off); off += 16384;
    u16* W3f    = (u16*)(base + off); off += 65536;
    u16* s1lf   = (u16*)(base + off); off += 65536;   // 256x128
    u16* s1rf   = (u16*)(base + off); off += 65536;
    u16* g1w1f  = (u16*)(base + off); off += 65536;   // 256x128
    u16* g1w2f  = (u16*)(base + off); off += 32768;   // 128x128
    u16* ga1f   = (u16*)(base + off); off += 40960;   // 256x80
    u16* s2lf   = (u16*)(base + off); off += 131072;  // 128x512
    u16* s2rf   = (u16*)(base + off); off += 131072;
    u16* g2w1f  = (u16*)(base + off); off += 32768;
    u16* g2w2f  = (u16*)(base + off); off += 32768;
    u16* glinf  = (u16*)(base + off); off += 131072;  // 128x512
    u16* ga2f   = (u16*)(base + off); off += 131072;  // 80(->128)x512
    u16* l1f    = (u16*)(base + off); off += 524288;  // 512x512
    u16* l2f    = (u16*)(base + off); off += 524288;

    k_init<<<40, 256, 0, stream>>>(counts, ssum, ssq);
    k_cvt_x<<<2048, 256, 0, stream>>>(x, (u32*)xb);
    k_wfrag<<<128, 256, 0, stream>>>(Wp1, Wp2, Wp3, W1f, W2f, W3f);
    k_pack<<<256, 256, 0, stream>>>(sage1_Wl, s1lf, 256, 8);
    k_pack<<<256, 256, 0, stream>>>(sage1_Wr, s1rf, 256, 8);
    k_pack<<<256, 256, 0, stream>>>(gin1_W1,  g1w1f, 256, 8);
    k_pack<<<256, 256, 0, stream>>>(gin1_W2,  g1w2f, 128, 8);
    k_pack<<<256, 256, 0, stream>>>(gat1_W,   ga1f, 256, 5);
    k_pack<<<256, 256, 0, stream>>>(sage2_Wl, s2lf, 128, 32);
    k_pack<<<256, 256, 0, stream>>>(sage2_Wr, s2rf, 128, 32);
    k_pack<<<256, 256, 0, stream>>>(gin2_W1,  g2w1f, 128, 8);
    k_pack<<<256, 256, 0, stream>>>(gin2_W2,  g2w2f, 128, 8);
    k_pack<<<256, 256, 0, stream>>>(gin_lin_W, glinf, 128, 32);
    k_pack<<<256, 256, 0, stream>>>(gat2_W,   ga2f, 80, 32);
    k_pack<<<256, 256, 0, stream>>>(lin1_W,   l1f, 512, 32);
    k_pack<<<256, 256, 0, stream>>>(lin2_W,   l2f, 512, 32);

    k_pointnet_mfma<<<NN, 256, 0, stream>>>(xb, W1f, bp1, W2f, bp2, W3f, bp3, featb);
    k_csr_count<<<(NE + 255) / 256, 256, 0, stream>>>(EI, counts);
    k_scan<<<1, 1024, 0, stream>>>(counts, offs, cursor);
    k_csr_scatter<<<(NE + 255) / 256, 256, 0, stream>>>(EI, cursor, csrc);

    dim3 gN128(4, 79), gN80(5, 79), gWide(4, 79);

    // aggregations on feat (bf16)
    k_aggb<128, 0><<<NN, 128, 0, stream>>>((const u32*)featb, (u32*)mean1, offs, csrc);
    k_aggb<128, 1><<<NN, 128, 0, stream>>>((const u32*)featb, (u32*)agg1, offs, csrc);

    // SAGE1: hs = relu(mean1@Wl + feat@Wr + bl)
    k_mm<2,1,1,0,0><<<gN128, 256, 0, stream>>>(mean1, featb, s1lf, s1rf, sage1_bl,
                                               256, 8, hsb, nullptr, 0, nullptr, nullptr);
    // GIN1
    k_mm<2,0,1,0,0><<<gN128, 256, 0, stream>>>(agg1, nullptr, g1w1f, nullptr, gin1_b1,
                                               256, 8, g1, nullptr, 0, nullptr, nullptr);
    k_mm<2,0,1,0,0><<<gN128, 256, 0, stream>>>(g1, nullptr, g1w2f, nullptr, gin1_b2,
                                               128, 8, g2, nullptr, 0, nullptr, nullptr);
    // GAT1
    k_mm<1,0,0,0,0><<<gN80, 256, 0, stream>>>(featb, nullptr, ga1f, nullptr, nullptr,
                                              256, 5, hgat, nullptr, 0, nullptr, nullptr);
    k_gat1_al<<<1250, 64, 0, stream>>>(hgat, gat1_as, gat1_ad, als1, ald1);
    k_gat1_attn<<<NN, 128, 0, stream>>>(hgat, als1, ald1, gat1_b, offs, csrc, hab);

    // SAGE2: Y = w0*(mean2@Wl + hs@Wr + bl)
    k_aggb<64, 0><<<NN, 64, 0, stream>>>((const u32*)hsb, (u32*)mean2, offs, csrc);
    k_mm<8,1,0,1,0><<<gWide, 256, 0, stream>>>(mean2, hsb, s2lf, s2rf, sage2_bl,
                                               128, 32, Y, fusion_w, 0, nullptr, nullptr);
    // GIN2
    k_aggb<64, 1><<<NN, 64, 0, stream>>>((const u32*)g2, (u32*)g1, offs, csrc);
    k_mm<2,0,1,0,0><<<gN128, 256, 0, stream>>>(g1, nullptr, g2w1f, nullptr, gin2_b1,
                                               128, 8, g2, nullptr, 0, nullptr, nullptr);
    k_mm<2,0,1,0,0><<<gN128, 256, 0, stream>>>(g2, nullptr, g2w2f, nullptr, gin2_b2,
                                               128, 8, g1, nullptr, 0, nullptr, nullptr);
    k_mm<8,0,0,2,0><<<gWide, 256, 0, stream>>>(g1, nullptr, glinf, nullptr, gin_lin_b,
                                               128, 32, Y, fusion_w, 1, nullptr, nullptr);
    // GAT2
    k_mm<8,0,0,0,0><<<gWide, 256, 0, stream>>>(hab, nullptr, ga2f, nullptr, nullptr,
                                               80, 32, h2b, nullptr, 0, nullptr, nullptr);
    k_gat2_al<<<NN, 256, 0, stream>>>(h2b, gat2_as, gat2_ad, als2, ald2);
    k_gat2_attn<<<NN, 256, 0, stream>>>(h2b, als2, ald2, gat2_b, offs, csrc, fusion_w, Y);

    // BN (stats only; apply fused into lin1 staging) + head
    k_bn_stats<<<250, 256, 0, stream>>>(Y, ssum, ssq);
    k_bn_final<<<2, 256, 0, stream>>>(ssum, ssq, mu, inv);
    k_mm<8,0,1,0,1><<<gWide, 256, 0, stream>>>((const u16*)Y, nullptr, l1f, nullptr, lin1_b,
                                               512, 32, y1b, nullptr, 0, mu, inv);
    k_mm<8,0,0,3,0><<<gWide, 256, 0, stream>>>(y1b, nullptr, l2f, nullptr, lin2_b,
                                               512, 32, y2, nullptr, 0, nullptr, nullptr);

    k_final<<<(NT + 3) / 4, 256, 0, stream>>>(y2, EI, tid, fc2_W, fc2_b, (float*)d_out);
}